// Round 1
// baseline (548.414 us; speedup 1.0000x reference)
//
#include <hip/hip_runtime.h>
#include <math.h>

#define B_ 32
#define P_ 512
#define N_ 1024
#define E_ 128
#define H_ 8
#define D_ 16

__device__ __forceinline__ float dot4(float4 a, float4 b) {
  return fmaf(a.x, b.x, fmaf(a.y, b.y, fmaf(a.z, b.z, a.w * b.w)));
}
__device__ __forceinline__ void fma4(float4& acc, float a, float4 w) {
  acc.x = fmaf(a, w.x, acc.x); acc.y = fmaf(a, w.y, acc.y);
  acc.z = fmaf(a, w.z, acc.z); acc.w = fmaf(a, w.w, acc.w);
}
__device__ __forceinline__ void add4(float4& acc, float4 w) {
  acc.x += w.x; acc.y += w.y; acc.z += w.z; acc.w += w.w;
}
__device__ __forceinline__ float fast_tanh(float x) {
  x = fminf(20.f, fmaxf(-20.f, x));
  float e = __expf(2.f * x);
  return (e - 1.f) / (e + 1.f);
}

// ---------------------------------------------------------------------------
// C[M,128] = A[M,128] @ W[128,128]  (+ optional rank-1 ea⊗ew, + optional bias)
// One block = 128 rows x 128 cols. 256 threads, 4x16 micro-tile per thread.
// ---------------------------------------------------------------------------
__global__ __launch_bounds__(256, 2) void gemm128(
    const float* __restrict__ A, const float* __restrict__ W,
    const float* __restrict__ ea, const float* __restrict__ ew,
    const float* __restrict__ bias, float* __restrict__ C) {
  __shared__ float As[128][33];   // [row][k] pad -> 4-way max on reads
  __shared__ float Ws[32][128];   // [k][col]
  const int tid = threadIdx.x;
  const size_t m0 = (size_t)blockIdx.x * 128;
  const int tr = tid >> 3, tc = tid & 7;
  const int r0 = tr * 4;
  const int c0 = tc * 16;

  float4 acc[4][4];
#pragma unroll
  for (int j = 0; j < 4; ++j)
#pragma unroll
    for (int i = 0; i < 4; ++i) acc[j][i] = make_float4(0.f, 0.f, 0.f, 0.f);

  for (int kb = 0; kb < 4; ++kb) {
    __syncthreads();
    {
      int idx = tid;
#pragma unroll
      for (int it = 0; it < 4; ++it, idx += 256) {
        int r = idx >> 3, k4 = idx & 7;
        float4 v = reinterpret_cast<const float4*>(A + (m0 + r) * 128 + kb * 32)[k4];
        As[r][k4 * 4 + 0] = v.x; As[r][k4 * 4 + 1] = v.y;
        As[r][k4 * 4 + 2] = v.z; As[r][k4 * 4 + 3] = v.w;
      }
      idx = tid;
#pragma unroll
      for (int it = 0; it < 4; ++it, idx += 256) {
        int kk = idx >> 5, c4 = idx & 31;
        reinterpret_cast<float4*>(&Ws[kk][0])[c4] =
            reinterpret_cast<const float4*>(W + (size_t)(kb * 32 + kk) * 128)[c4];
      }
    }
    __syncthreads();
#pragma unroll 8
    for (int kk = 0; kk < 32; ++kk) {
      float a0 = As[r0 + 0][kk], a1 = As[r0 + 1][kk];
      float a2 = As[r0 + 2][kk], a3 = As[r0 + 3][kk];
      const float4* wr = reinterpret_cast<const float4*>(&Ws[kk][c0]);
      float4 w0 = wr[0], w1 = wr[1], w2 = wr[2], w3 = wr[3];
      fma4(acc[0][0], a0, w0); fma4(acc[0][1], a0, w1); fma4(acc[0][2], a0, w2); fma4(acc[0][3], a0, w3);
      fma4(acc[1][0], a1, w0); fma4(acc[1][1], a1, w1); fma4(acc[1][2], a1, w2); fma4(acc[1][3], a1, w3);
      fma4(acc[2][0], a2, w0); fma4(acc[2][1], a2, w1); fma4(acc[2][2], a2, w2); fma4(acc[2][3], a2, w3);
      fma4(acc[3][0], a3, w0); fma4(acc[3][1], a3, w1); fma4(acc[3][2], a3, w2); fma4(acc[3][3], a3, w3);
    }
  }

  if (ea != nullptr) {  // concat column: C += ea[r] * ew[c]
    const float4* ew4 = reinterpret_cast<const float4*>(ew + c0);
    float4 e0 = ew4[0], e1 = ew4[1], e2 = ew4[2], e3 = ew4[3];
#pragma unroll
    for (int j = 0; j < 4; ++j) {
      float av = ea[m0 + r0 + j];
      fma4(acc[j][0], av, e0); fma4(acc[j][1], av, e1);
      fma4(acc[j][2], av, e2); fma4(acc[j][3], av, e3);
    }
  }
  if (bias != nullptr) {
    const float4* b4 = reinterpret_cast<const float4*>(bias + c0);
    float4 b0 = b4[0], b1 = b4[1], b2 = b4[2], b3 = b4[3];
#pragma unroll
    for (int j = 0; j < 4; ++j) {
      add4(acc[j][0], b0); add4(acc[j][1], b1); add4(acc[j][2], b2); add4(acc[j][3], b3);
    }
  }
#pragma unroll
  for (int j = 0; j < 4; ++j) {
    float4* c4p = reinterpret_cast<float4*>(C + (m0 + r0 + j) * 128 + c0);
    c4p[0] = acc[j][0]; c4p[1] = acc[j][1]; c4p[2] = acc[j][2]; c4p[3] = acc[j][3];
  }
}

// ---------------------------------------------------------------------------
// Fused attention: one thread owns one (b,h,p) row. Online softmax in regs.
// grid (2, H, B), 256 threads. K/V staged in LDS in chunks of 32 n.
// ---------------------------------------------------------------------------
__global__ __launch_bounds__(256, 2) void attn_kernel(
    const float* __restrict__ Q, const float* __restrict__ K,
    const float* __restrict__ V, const float* __restrict__ mask,
    float* __restrict__ O) {
  const int b = blockIdx.z, h = blockIdx.y;
  const int p = blockIdx.x * 256 + threadIdx.x;
  const int t = threadIdx.x;
  __shared__ float Ks[32][16];
  __shared__ float Vs[32][16];

  const size_t qoff = (size_t)(b * P_ + p) * E_ + h * D_;
  float4 qv[4];
#pragma unroll
  for (int i = 0; i < 4; ++i) qv[i] = reinterpret_cast<const float4*>(Q + qoff)[i];
  float4 out[4];
#pragma unroll
  for (int i = 0; i < 4; ++i) out[i] = make_float4(0.f, 0.f, 0.f, 0.f);
  float m = -1e30f, l = 0.f;
  const float* mrow = mask + (size_t)(b * P_ + p) * N_;

  for (int c = 0; c < N_ / 32; ++c) {
    __syncthreads();
    {
      const int n = (t & 127) >> 2, d4 = t & 3;
      if (t < 128) {
        reinterpret_cast<float4*>(&Ks[n][0])[d4] =
            reinterpret_cast<const float4*>(K + (size_t)(b * N_ + c * 32 + n) * E_ + h * D_)[d4];
      } else {
        reinterpret_cast<float4*>(&Vs[n][0])[d4] =
            reinterpret_cast<const float4*>(V + (size_t)(b * N_ + c * 32 + n) * E_ + h * D_)[d4];
      }
    }
    __syncthreads();

    float mk[32];
#pragma unroll
    for (int i = 0; i < 8; ++i) {
      float4 mv = reinterpret_cast<const float4*>(mrow + c * 32)[i];
      mk[i * 4 + 0] = mv.x; mk[i * 4 + 1] = mv.y; mk[i * 4 + 2] = mv.z; mk[i * 4 + 3] = mv.w;
    }
    float s[32];
    float cmax = -1e30f;
#pragma unroll
    for (int j = 0; j < 32; ++j) {
      const float4* kr = reinterpret_cast<const float4*>(&Ks[j][0]);
      float d = dot4(qv[0], kr[0]) + dot4(qv[1], kr[1]) + dot4(qv[2], kr[2]) + dot4(qv[3], kr[3]);
      float sv = fmaf(d, 0.25f, mk[j]);
      s[j] = sv;
      cmax = fmaxf(cmax, sv);
    }
    const float nm = fmaxf(m, cmax);
    const float f = __expf(m - nm);   // m=-1e30 first iter -> f=0, no NaN
    l *= f;
#pragma unroll
    for (int i = 0; i < 4; ++i) {
      out[i].x *= f; out[i].y *= f; out[i].z *= f; out[i].w *= f;
    }
#pragma unroll
    for (int j = 0; j < 32; ++j) {
      const float w = __expf(s[j] - nm);
      l += w;
      const float4* vr = reinterpret_cast<const float4*>(&Vs[j][0]);
      fma4(out[0], w, vr[0]); fma4(out[1], w, vr[1]);
      fma4(out[2], w, vr[2]); fma4(out[3], w, vr[3]);
    }
    m = nm;
  }
  const float inv = 1.f / l;
  float4* o4 = reinterpret_cast<float4*>(O + qoff);
#pragma unroll
  for (int i = 0; i < 4; ++i) {
    float4 ov = out[i];
    ov.x *= inv; ov.y *= inv; ov.z *= inv; ov.w *= inv;
    o4[i] = ov;
  }
}

// ---------------------------------------------------------------------------
// T[b,p,n] = 10*tanh((mh[b,p,:]·enc[b,n,:])/sqrt(128)) + mask[b,p,n]
// grid (N/128, P/128, B), 256 threads, 128x128 tile, BK=32.
// ---------------------------------------------------------------------------
__global__ __launch_bounds__(256, 2) void logits_kernel(
    const float* __restrict__ mh, const float* __restrict__ enc,
    const float* __restrict__ mask, float* __restrict__ T) {
  const int b = blockIdx.z;
  const int p0 = blockIdx.y * 128;
  const int n0 = blockIdx.x * 128;
  __shared__ float As[128][33];    // mh tile [p][k]
  __shared__ float Bs[32][132];    // enc tile transposed [k][n], 16B-aligned rows
  const int tid = threadIdx.x;
  const int tr = tid >> 3, tc = tid & 7;
  const int r0 = tr * 4, c0 = tc * 16;
  const float* Ab = mh + ((size_t)b * P_ + p0) * E_;
  const float* Eb = enc + (size_t)b * N_ * E_;

  float4 acc[4][4];
#pragma unroll
  for (int j = 0; j < 4; ++j)
#pragma unroll
    for (int i = 0; i < 4; ++i) acc[j][i] = make_float4(0.f, 0.f, 0.f, 0.f);

  for (int kb = 0; kb < 4; ++kb) {
    __syncthreads();
    int idx = tid;
#pragma unroll
    for (int it = 0; it < 4; ++it, idx += 256) {
      int r = idx >> 3, k4 = idx & 7;
      float4 v = reinterpret_cast<const float4*>(Ab + (size_t)r * 128 + kb * 32)[k4];
      As[r][k4 * 4 + 0] = v.x; As[r][k4 * 4 + 1] = v.y;
      As[r][k4 * 4 + 2] = v.z; As[r][k4 * 4 + 3] = v.w;
    }
    idx = tid;
#pragma unroll
    for (int it = 0; it < 4; ++it, idx += 256) {
      int nn = idx >> 3, k4 = idx & 7;
      float4 v = reinterpret_cast<const float4*>(Eb + (size_t)(n0 + nn) * 128 + kb * 32)[k4];
      Bs[k4 * 4 + 0][nn] = v.x; Bs[k4 * 4 + 1][nn] = v.y;
      Bs[k4 * 4 + 2][nn] = v.z; Bs[k4 * 4 + 3][nn] = v.w;
    }
    __syncthreads();
#pragma unroll 8
    for (int kk = 0; kk < 32; ++kk) {
      float a0 = As[r0 + 0][kk], a1 = As[r0 + 1][kk];
      float a2 = As[r0 + 2][kk], a3 = As[r0 + 3][kk];
      const float4* br = reinterpret_cast<const float4*>(&Bs[kk][c0]);
      float4 w0 = br[0], w1 = br[1], w2 = br[2], w3 = br[3];
      fma4(acc[0][0], a0, w0); fma4(acc[0][1], a0, w1); fma4(acc[0][2], a0, w2); fma4(acc[0][3], a0, w3);
      fma4(acc[1][0], a1, w0); fma4(acc[1][1], a1, w1); fma4(acc[1][2], a1, w2); fma4(acc[1][3], a1, w3);
      fma4(acc[2][0], a2, w0); fma4(acc[2][1], a2, w1); fma4(acc[2][2], a2, w2); fma4(acc[2][3], a2, w3);
      fma4(acc[3][0], a3, w0); fma4(acc[3][1], a3, w1); fma4(acc[3][2], a3, w2); fma4(acc[3][3], a3, w3);
    }
  }

  const float inv_s = 0.08838834764831845f;  // 1/sqrt(128)
#pragma unroll
  for (int j = 0; j < 4; ++j) {
    const size_t prow = ((size_t)b * P_ + p0 + r0 + j) * N_ + n0 + c0;
    const float4* mk4 = reinterpret_cast<const float4*>(mask + prow);
    float4* t4 = reinterpret_cast<float4*>(T + prow);
#pragma unroll
    for (int i = 0; i < 4; ++i) {
      float4 a = acc[j][i];
      float4 mv = mk4[i];
      float4 o;
      o.x = fmaf(10.f, fast_tanh(a.x * inv_s), mv.x);
      o.y = fmaf(10.f, fast_tanh(a.y * inv_s), mv.y);
      o.z = fmaf(10.f, fast_tanh(a.z * inv_s), mv.z);
      o.w = fmaf(10.f, fast_tanh(a.w * inv_s), mv.w);
      t4[i] = o;
    }
  }
}

// ---------------------------------------------------------------------------
// probs[row,:] = softmax(T[row,:] * 10)   (temp 0.1 folded)
// one block per row, 256 threads x float4 = 1024 cols
// ---------------------------------------------------------------------------
__global__ __launch_bounds__(256, 4) void softmax_rows(
    const float* __restrict__ T, float* __restrict__ O) {
  const size_t row = blockIdx.x;
  const int tid = threadIdx.x;
  const float4 v = reinterpret_cast<const float4*>(T + row * N_)[tid];
  float lm = fmaxf(fmaxf(v.x, v.y), fmaxf(v.z, v.w));
#pragma unroll
  for (int o = 32; o; o >>= 1) lm = fmaxf(lm, __shfl_xor(lm, o));
  __shared__ float red[8];
  const int wave = tid >> 6, lane = tid & 63;
  if (lane == 0) red[wave] = lm;
  __syncthreads();
  const float m = fmaxf(fmaxf(red[0], red[1]), fmaxf(red[2], red[3]));
  float4 w;
  w.x = __expf((v.x - m) * 10.f);
  w.y = __expf((v.y - m) * 10.f);
  w.z = __expf((v.z - m) * 10.f);
  w.w = __expf((v.w - m) * 10.f);
  float ls = w.x + w.y + w.z + w.w;
#pragma unroll
  for (int o = 32; o; o >>= 1) ls += __shfl_xor(ls, o);
  if (lane == 0) red[4 + wave] = ls;
  __syncthreads();
  const float inv = 1.f / (red[4] + red[5] + red[6] + red[7]);
  float4 o4;
  o4.x = w.x * inv; o4.y = w.y * inv; o4.z = w.z * inv; o4.w = w.w * inv;
  reinterpret_cast<float4*>(O + row * N_)[tid] = o4;
}

extern "C" void kernel_launch(void* const* d_in, const int* in_sizes, int n_in,
                              void* d_out, int out_size, void* d_ws, size_t ws_size,
                              hipStream_t stream) {
  const float* eln  = (const float*)d_in[0];  // [B,P,E]
  const float* load = (const float*)d_in[1];  // [B,P]
  const float* mask = (const float*)d_in[2];  // [B,P,N]
  const float* enc  = (const float*)d_in[3];  // [B,N,E]
  const float* Wq   = (const float*)d_in[4];  // [E+1,E]
  const float* Wk   = (const float*)d_in[5];  // [E,E]
  const float* Wv   = (const float*)d_in[6];  // [E,E]
  const float* Wc   = (const float*)d_in[7];  // [E,E]
  const float* bc   = (const float*)d_in[8];  // [E]
  float* out = (float*)d_out;

  float* ws    = (float*)d_ws;
  float* kbuf  = ws;                                   // [B*N,E]
  float* vbuf  = kbuf  + (size_t)B_ * N_ * E_;         // [B*N,E]
  float* qbuf  = vbuf  + (size_t)B_ * N_ * E_;         // [B*P,E]
  float* abuf  = qbuf  + (size_t)B_ * P_ * E_;         // [B*P,E] attention out
  float* mhbuf = abuf  + (size_t)B_ * P_ * E_;         // [B*P,E]
  float* tbuf  = mhbuf + (size_t)B_ * P_ * E_;         // [B*P,N] logits

  // K = enc @ Wk ; V = enc @ Wv   (M = B*N = 32768 -> 256 blocks)
  gemm128<<<dim3(256), 256, 0, stream>>>(enc, Wk, nullptr, nullptr, nullptr, kbuf);
  gemm128<<<dim3(256), 256, 0, stream>>>(enc, Wv, nullptr, nullptr, nullptr, vbuf);
  // q = [eln | load] @ Wq_last    (M = B*P = 16384 -> 128 blocks)
  gemm128<<<dim3(128), 256, 0, stream>>>(eln, Wq, load, Wq + 128 * 128, nullptr, qbuf);
  // multi-head attention
  attn_kernel<<<dim3(2, H_, B_), 256, 0, stream>>>(qbuf, kbuf, vbuf, mask, abuf);
  // mh = attn_out @ Wc + bc
  gemm128<<<dim3(128), 256, 0, stream>>>(abuf, Wc, nullptr, nullptr, bc, mhbuf);
  // logits = 10*tanh(mh·encT/sqrt(128)) + mask
  logits_kernel<<<dim3(8, 4, B_), 256, 0, stream>>>(mhbuf, enc, mask, tbuf);
  // probs = softmax(logits/0.1)
  softmax_rows<<<dim3(16384), 256, 0, stream>>>(tbuf, out);
}

// Round 2
// 498.710 us; speedup vs baseline: 1.0997x; 1.0997x over previous
//
#include <hip/hip_runtime.h>
#include <math.h>

#define B_ 32
#define P_ 512
#define N_ 1024
#define E_ 128
#define H_ 8
#define D_ 16
#define SPLIT_ 4
#define KEYS_ (N_ / SPLIT_)          // 256 keys per split
#define BHP_ (B_ * H_ * P_)          // 131072

__device__ __forceinline__ float dot4(float4 a, float4 b) {
  return fmaf(a.x, b.x, fmaf(a.y, b.y, fmaf(a.z, b.z, a.w * b.w)));
}
__device__ __forceinline__ void fma4(float4& acc, float a, float4 w) {
  acc.x = fmaf(a, w.x, acc.x); acc.y = fmaf(a, w.y, acc.y);
  acc.z = fmaf(a, w.z, acc.z); acc.w = fmaf(a, w.w, acc.w);
}
__device__ __forceinline__ void add4(float4& acc, float4 w) {
  acc.x += w.x; acc.y += w.y; acc.z += w.z; acc.w += w.w;
}
__device__ __forceinline__ float fast_tanh(float x) {
  x = fminf(20.f, fmaxf(-20.f, x));
  float e = __expf(2.f * x);
  return (e - 1.f) / (e + 1.f);
}

// ---------------------------------------------------------------------------
// C[M,128] = A[M,128] @ W[128,128]  (+ optional rank-1 ea⊗ew, + optional bias)
// One block = 128 rows x 128 cols. 256 threads, 4x16 micro-tile per thread.
// ---------------------------------------------------------------------------
__global__ __launch_bounds__(256, 2) void gemm128(
    const float* __restrict__ A, const float* __restrict__ W,
    const float* __restrict__ ea, const float* __restrict__ ew,
    const float* __restrict__ bias, float* __restrict__ C) {
  __shared__ float As[128][33];
  __shared__ float Ws[32][128];
  const int tid = threadIdx.x;
  const size_t m0 = (size_t)blockIdx.x * 128;
  const int tr = tid >> 3, tc = tid & 7;
  const int r0 = tr * 4;
  const int c0 = tc * 16;

  float4 acc[4][4];
#pragma unroll
  for (int j = 0; j < 4; ++j)
#pragma unroll
    for (int i = 0; i < 4; ++i) acc[j][i] = make_float4(0.f, 0.f, 0.f, 0.f);

  for (int kb = 0; kb < 4; ++kb) {
    __syncthreads();
    {
      int idx = tid;
#pragma unroll
      for (int it = 0; it < 4; ++it, idx += 256) {
        int r = idx >> 3, k4 = idx & 7;
        float4 v = reinterpret_cast<const float4*>(A + (m0 + r) * 128 + kb * 32)[k4];
        As[r][k4 * 4 + 0] = v.x; As[r][k4 * 4 + 1] = v.y;
        As[r][k4 * 4 + 2] = v.z; As[r][k4 * 4 + 3] = v.w;
      }
      idx = tid;
#pragma unroll
      for (int it = 0; it < 4; ++it, idx += 256) {
        int kk = idx >> 5, c4 = idx & 31;
        reinterpret_cast<float4*>(&Ws[kk][0])[c4] =
            reinterpret_cast<const float4*>(W + (size_t)(kb * 32 + kk) * 128)[c4];
      }
    }
    __syncthreads();
#pragma unroll 8
    for (int kk = 0; kk < 32; ++kk) {
      float a0 = As[r0 + 0][kk], a1 = As[r0 + 1][kk];
      float a2 = As[r0 + 2][kk], a3 = As[r0 + 3][kk];
      const float4* wr = reinterpret_cast<const float4*>(&Ws[kk][c0]);
      float4 w0 = wr[0], w1 = wr[1], w2 = wr[2], w3 = wr[3];
      fma4(acc[0][0], a0, w0); fma4(acc[0][1], a0, w1); fma4(acc[0][2], a0, w2); fma4(acc[0][3], a0, w3);
      fma4(acc[1][0], a1, w0); fma4(acc[1][1], a1, w1); fma4(acc[1][2], a1, w2); fma4(acc[1][3], a1, w3);
      fma4(acc[2][0], a2, w0); fma4(acc[2][1], a2, w1); fma4(acc[2][2], a2, w2); fma4(acc[2][3], a2, w3);
      fma4(acc[3][0], a3, w0); fma4(acc[3][1], a3, w1); fma4(acc[3][2], a3, w2); fma4(acc[3][3], a3, w3);
    }
  }

  if (ea != nullptr) {
    const float4* ew4 = reinterpret_cast<const float4*>(ew + c0);
    float4 e0 = ew4[0], e1 = ew4[1], e2 = ew4[2], e3 = ew4[3];
#pragma unroll
    for (int j = 0; j < 4; ++j) {
      float av = ea[m0 + r0 + j];
      fma4(acc[j][0], av, e0); fma4(acc[j][1], av, e1);
      fma4(acc[j][2], av, e2); fma4(acc[j][3], av, e3);
    }
  }
  if (bias != nullptr) {
    const float4* b4 = reinterpret_cast<const float4*>(bias + c0);
    float4 b0 = b4[0], b1 = b4[1], b2 = b4[2], b3 = b4[3];
#pragma unroll
    for (int j = 0; j < 4; ++j) {
      add4(acc[j][0], b0); add4(acc[j][1], b1); add4(acc[j][2], b2); add4(acc[j][3], b3);
    }
  }
#pragma unroll
  for (int j = 0; j < 4; ++j) {
    float4* c4p = reinterpret_cast<float4*>(C + (m0 + r0 + j) * 128 + c0);
    c4p[0] = acc[j][0]; c4p[1] = acc[j][1]; c4p[2] = acc[j][2]; c4p[3] = acc[j][3];
  }
}

// ---------------------------------------------------------------------------
// Fused K/V projection: K = enc@Wk, V = enc@Wv sharing the A tile.
// ---------------------------------------------------------------------------
__global__ __launch_bounds__(256, 1) void gemm_kv(
    const float* __restrict__ A, const float* __restrict__ Wk,
    const float* __restrict__ Wv, float* __restrict__ Ko, float* __restrict__ Vo) {
  __shared__ float As[128][33];
  __shared__ float Wks[32][128];
  __shared__ float Wvs[32][128];
  const int tid = threadIdx.x;
  const size_t m0 = (size_t)blockIdx.x * 128;
  const int tr = tid >> 3, tc = tid & 7;
  const int r0 = tr * 4;
  const int c0 = tc * 16;

  float4 acck[4][4], accv[4][4];
#pragma unroll
  for (int j = 0; j < 4; ++j)
#pragma unroll
    for (int i = 0; i < 4; ++i) {
      acck[j][i] = make_float4(0.f, 0.f, 0.f, 0.f);
      accv[j][i] = make_float4(0.f, 0.f, 0.f, 0.f);
    }

  for (int kb = 0; kb < 4; ++kb) {
    __syncthreads();
    {
      int idx = tid;
#pragma unroll
      for (int it = 0; it < 4; ++it, idx += 256) {
        int r = idx >> 3, k4 = idx & 7;
        float4 v = reinterpret_cast<const float4*>(A + (m0 + r) * 128 + kb * 32)[k4];
        As[r][k4 * 4 + 0] = v.x; As[r][k4 * 4 + 1] = v.y;
        As[r][k4 * 4 + 2] = v.z; As[r][k4 * 4 + 3] = v.w;
      }
      idx = tid;
#pragma unroll
      for (int it = 0; it < 4; ++it, idx += 256) {
        int kk = idx >> 5, c4 = idx & 31;
        reinterpret_cast<float4*>(&Wks[kk][0])[c4] =
            reinterpret_cast<const float4*>(Wk + (size_t)(kb * 32 + kk) * 128)[c4];
      }
      idx = tid;
#pragma unroll
      for (int it = 0; it < 4; ++it, idx += 256) {
        int kk = idx >> 5, c4 = idx & 31;
        reinterpret_cast<float4*>(&Wvs[kk][0])[c4] =
            reinterpret_cast<const float4*>(Wv + (size_t)(kb * 32 + kk) * 128)[c4];
      }
    }
    __syncthreads();
#pragma unroll 4
    for (int kk = 0; kk < 32; ++kk) {
      float a0 = As[r0 + 0][kk], a1 = As[r0 + 1][kk];
      float a2 = As[r0 + 2][kk], a3 = As[r0 + 3][kk];
      const float4* wkr = reinterpret_cast<const float4*>(&Wks[kk][c0]);
      const float4* wvr = reinterpret_cast<const float4*>(&Wvs[kk][c0]);
#pragma unroll
      for (int i = 0; i < 4; ++i) {
        float4 wk = wkr[i], wv = wvr[i];
        fma4(acck[0][i], a0, wk); fma4(acck[1][i], a1, wk);
        fma4(acck[2][i], a2, wk); fma4(acck[3][i], a3, wk);
        fma4(accv[0][i], a0, wv); fma4(accv[1][i], a1, wv);
        fma4(accv[2][i], a2, wv); fma4(accv[3][i], a3, wv);
      }
    }
  }
#pragma unroll
  for (int j = 0; j < 4; ++j) {
    float4* k4p = reinterpret_cast<float4*>(Ko + (m0 + r0 + j) * 128 + c0);
    float4* v4p = reinterpret_cast<float4*>(Vo + (m0 + r0 + j) * 128 + c0);
#pragma unroll
    for (int i = 0; i < 4; ++i) { k4p[i] = acck[j][i]; v4p[i] = accv[j][i]; }
  }
}

// ---------------------------------------------------------------------------
// Flash-decoding pass: each block handles 256 p-rows x 256 keys of one (b,h).
// Writes UNNORMALIZED partial out + (m,l) per row. grid (2*SPLIT, H, B).
// ---------------------------------------------------------------------------
__global__ __launch_bounds__(256, 4) void attn_pass(
    const float* __restrict__ Q, const float* __restrict__ K,
    const float* __restrict__ V, const float* __restrict__ mask,
    float* __restrict__ pout, float* __restrict__ pml) {
  const int b = blockIdx.z, h = blockIdx.y;
  const int s = blockIdx.x >> 1;
  const int pt = blockIdx.x & 1;
  const int t = threadIdx.x;
  const int p = pt * 256 + t;
  const int k0 = s * KEYS_;
  __shared__ float Ks[64][16];
  __shared__ float Vs[64][16];

  const size_t qoff = (size_t)(b * P_ + p) * E_ + h * D_;
  float4 qv[4];
#pragma unroll
  for (int i = 0; i < 4; ++i) qv[i] = reinterpret_cast<const float4*>(Q + qoff)[i];
  float4 out[4];
#pragma unroll
  for (int i = 0; i < 4; ++i) out[i] = make_float4(0.f, 0.f, 0.f, 0.f);
  float m = -1e30f, l = 0.f;
  const float* mrow = mask + (size_t)(b * P_ + p) * N_ + k0;

  for (int c = 0; c < KEYS_ / 64; ++c) {
    __syncthreads();
    {
      const int n = t >> 2, d4 = t & 3;
      const size_t goff = (size_t)(b * N_ + k0 + c * 64 + n) * E_ + h * D_;
      reinterpret_cast<float4*>(&Ks[n][0])[d4] = reinterpret_cast<const float4*>(K + goff)[d4];
      reinterpret_cast<float4*>(&Vs[n][0])[d4] = reinterpret_cast<const float4*>(V + goff)[d4];
    }
    __syncthreads();
#pragma unroll
    for (int half = 0; half < 2; ++half) {
      const int j0 = half * 32;
      float sarr[32];
#pragma unroll
      for (int i = 0; i < 8; ++i) {
        float4 mv = reinterpret_cast<const float4*>(mrow + c * 64 + j0)[i];
        sarr[i * 4 + 0] = mv.x; sarr[i * 4 + 1] = mv.y;
        sarr[i * 4 + 2] = mv.z; sarr[i * 4 + 3] = mv.w;
      }
      float cmax = -1e30f;
#pragma unroll
      for (int j = 0; j < 32; ++j) {
        const float4* kr = reinterpret_cast<const float4*>(&Ks[j0 + j][0]);
        float d = dot4(qv[0], kr[0]) + dot4(qv[1], kr[1]) + dot4(qv[2], kr[2]) + dot4(qv[3], kr[3]);
        float sv = fmaf(d, 0.25f, sarr[j]);
        sarr[j] = sv;
        cmax = fmaxf(cmax, sv);
      }
      const float nm = fmaxf(m, cmax);
      const float f = __expf(m - nm);
      l *= f;
#pragma unroll
      for (int i = 0; i < 4; ++i) {
        out[i].x *= f; out[i].y *= f; out[i].z *= f; out[i].w *= f;
      }
#pragma unroll
      for (int j = 0; j < 32; ++j) {
        const float w = __expf(sarr[j] - nm);
        l += w;
        const float4* vr = reinterpret_cast<const float4*>(&Vs[j0 + j][0]);
        fma4(out[0], w, vr[0]); fma4(out[1], w, vr[1]);
        fma4(out[2], w, vr[2]); fma4(out[3], w, vr[3]);
      }
      m = nm;
    }
  }
  const size_t idx = (size_t)(b * H_ + h) * P_ + p;
  float4* po = reinterpret_cast<float4*>(pout + ((size_t)s * BHP_ + idx) * 16);
  po[0] = out[0]; po[1] = out[1]; po[2] = out[2]; po[3] = out[3];
  reinterpret_cast<float2*>(pml)[(size_t)s * BHP_ + idx] = make_float2(m, l);
}

// ---------------------------------------------------------------------------
// Combine SPLIT_ partials -> normalized attention output in [B,P,H*D] layout.
// ---------------------------------------------------------------------------
__global__ __launch_bounds__(256, 8) void attn_combine(
    const float* __restrict__ pout, const float* __restrict__ pml,
    float* __restrict__ O) {
  const int idx = blockIdx.x * 256 + threadIdx.x;   // over B*H*P
  const int b = idx >> 12;
  const int h = (idx >> 9) & 7;
  const int p = idx & 511;
  float ms[SPLIT_], ls[SPLIT_];
  float M = -1e30f;
#pragma unroll
  for (int s = 0; s < SPLIT_; ++s) {
    float2 ml = reinterpret_cast<const float2*>(pml)[(size_t)s * BHP_ + idx];
    ms[s] = ml.x; ls[s] = ml.y;
    M = fmaxf(M, ms[s]);
  }
  float4 acc[4];
#pragma unroll
  for (int i = 0; i < 4; ++i) acc[i] = make_float4(0.f, 0.f, 0.f, 0.f);
  float L = 0.f;
#pragma unroll
  for (int s = 0; s < SPLIT_; ++s) {
    const float w = __expf(ms[s] - M);
    L = fmaf(ls[s], w, L);
    const float4* po = reinterpret_cast<const float4*>(pout + ((size_t)s * BHP_ + idx) * 16);
    fma4(acc[0], w, po[0]); fma4(acc[1], w, po[1]);
    fma4(acc[2], w, po[2]); fma4(acc[3], w, po[3]);
  }
  const float inv = 1.f / L;
  float4* o4 = reinterpret_cast<float4*>(O + (size_t)(b * P_ + p) * E_ + h * D_);
#pragma unroll
  for (int i = 0; i < 4; ++i) {
    float4 ov = acc[i];
    ov.x *= inv; ov.y *= inv; ov.z *= inv; ov.w *= inv;
    o4[i] = ov;
  }
}

// ---------------------------------------------------------------------------
// T[b,p,n] = 10*tanh((mh[b,p,:]·enc[b,n,:])/sqrt(128)) + mask[b,p,n]
// ---------------------------------------------------------------------------
__global__ __launch_bounds__(256, 2) void logits_kernel(
    const float* __restrict__ mh, const float* __restrict__ enc,
    const float* __restrict__ mask, float* __restrict__ T) {
  const int b = blockIdx.z;
  const int p0 = blockIdx.y * 128;
  const int n0 = blockIdx.x * 128;
  __shared__ float As[128][33];
  __shared__ float Bs[32][132];
  const int tid = threadIdx.x;
  const int tr = tid >> 3, tc = tid & 7;
  const int r0 = tr * 4, c0 = tc * 16;
  const float* Ab = mh + ((size_t)b * P_ + p0) * E_;
  const float* Eb = enc + (size_t)b * N_ * E_;

  float4 acc[4][4];
#pragma unroll
  for (int j = 0; j < 4; ++j)
#pragma unroll
    for (int i = 0; i < 4; ++i) acc[j][i] = make_float4(0.f, 0.f, 0.f, 0.f);

  for (int kb = 0; kb < 4; ++kb) {
    __syncthreads();
    int idx = tid;
#pragma unroll
    for (int it = 0; it < 4; ++it, idx += 256) {
      int r = idx >> 3, k4 = idx & 7;
      float4 v = reinterpret_cast<const float4*>(Ab + (size_t)r * 128 + kb * 32)[k4];
      As[r][k4 * 4 + 0] = v.x; As[r][k4 * 4 + 1] = v.y;
      As[r][k4 * 4 + 2] = v.z; As[r][k4 * 4 + 3] = v.w;
    }
    idx = tid;
#pragma unroll
    for (int it = 0; it < 4; ++it, idx += 256) {
      int nn = idx >> 3, k4 = idx & 7;
      float4 v = reinterpret_cast<const float4*>(Eb + (size_t)(n0 + nn) * 128 + kb * 32)[k4];
      Bs[k4 * 4 + 0][nn] = v.x; Bs[k4 * 4 + 1][nn] = v.y;
      Bs[k4 * 4 + 2][nn] = v.z; Bs[k4 * 4 + 3][nn] = v.w;
    }
    __syncthreads();
#pragma unroll 8
    for (int kk = 0; kk < 32; ++kk) {
      float a0 = As[r0 + 0][kk], a1 = As[r0 + 1][kk];
      float a2 = As[r0 + 2][kk], a3 = As[r0 + 3][kk];
      const float4* br = reinterpret_cast<const float4*>(&Bs[kk][c0]);
      float4 w0 = br[0], w1 = br[1], w2 = br[2], w3 = br[3];
      fma4(acc[0][0], a0, w0); fma4(acc[0][1], a0, w1); fma4(acc[0][2], a0, w2); fma4(acc[0][3], a0, w3);
      fma4(acc[1][0], a1, w0); fma4(acc[1][1], a1, w1); fma4(acc[1][2], a1, w2); fma4(acc[1][3], a1, w3);
      fma4(acc[2][0], a2, w0); fma4(acc[2][1], a2, w1); fma4(acc[2][2], a2, w2); fma4(acc[2][3], a2, w3);
      fma4(acc[3][0], a3, w0); fma4(acc[3][1], a3, w1); fma4(acc[3][2], a3, w2); fma4(acc[3][3], a3, w3);
    }
  }

  const float inv_s = 0.08838834764831845f;  // 1/sqrt(128)
#pragma unroll
  for (int j = 0; j < 4; ++j) {
    const size_t prow = ((size_t)b * P_ + p0 + r0 + j) * N_ + n0 + c0;
    const float4* mk4 = reinterpret_cast<const float4*>(mask + prow);
    float4* t4 = reinterpret_cast<float4*>(T + prow);
#pragma unroll
    for (int i = 0; i < 4; ++i) {
      float4 a = acc[j][i];
      float4 mv = mk4[i];
      float4 o;
      o.x = fmaf(10.f, fast_tanh(a.x * inv_s), mv.x);
      o.y = fmaf(10.f, fast_tanh(a.y * inv_s), mv.y);
      o.z = fmaf(10.f, fast_tanh(a.z * inv_s), mv.z);
      o.w = fmaf(10.f, fast_tanh(a.w * inv_s), mv.w);
      t4[i] = o;
    }
  }
}

// ---------------------------------------------------------------------------
// probs[row,:] = softmax(T[row,:] * 10)
// ---------------------------------------------------------------------------
__global__ __launch_bounds__(256, 4) void softmax_rows(
    const float* __restrict__ T, float* __restrict__ O) {
  const size_t row = blockIdx.x;
  const int tid = threadIdx.x;
  const float4 v = reinterpret_cast<const float4*>(T + row * N_)[tid];
  float lm = fmaxf(fmaxf(v.x, v.y), fmaxf(v.z, v.w));
#pragma unroll
  for (int o = 32; o; o >>= 1) lm = fmaxf(lm, __shfl_xor(lm, o));
  __shared__ float red[8];
  const int wave = tid >> 6, lane = tid & 63;
  if (lane == 0) red[wave] = lm;
  __syncthreads();
  const float m = fmaxf(fmaxf(red[0], red[1]), fmaxf(red[2], red[3]));
  float4 w;
  w.x = __expf((v.x - m) * 10.f);
  w.y = __expf((v.y - m) * 10.f);
  w.z = __expf((v.z - m) * 10.f);
  w.w = __expf((v.w - m) * 10.f);
  float ls = w.x + w.y + w.z + w.w;
#pragma unroll
  for (int o = 32; o; o >>= 1) ls += __shfl_xor(ls, o);
  if (lane == 0) red[4 + wave] = ls;
  __syncthreads();
  const float inv = 1.f / (red[4] + red[5] + red[6] + red[7]);
  float4 o4;
  o4.x = w.x * inv; o4.y = w.y * inv; o4.z = w.z * inv; o4.w = w.w * inv;
  reinterpret_cast<float4*>(O + row * N_)[tid] = o4;
}

extern "C" void kernel_launch(void* const* d_in, const int* in_sizes, int n_in,
                              void* d_out, int out_size, void* d_ws, size_t ws_size,
                              hipStream_t stream) {
  const float* eln  = (const float*)d_in[0];
  const float* load = (const float*)d_in[1];
  const float* mask = (const float*)d_in[2];
  const float* enc  = (const float*)d_in[3];
  const float* Wq   = (const float*)d_in[4];
  const float* Wk   = (const float*)d_in[5];
  const float* Wv   = (const float*)d_in[6];
  const float* Wc   = (const float*)d_in[7];
  const float* bc   = (const float*)d_in[8];
  float* out = (float*)d_out;

  const size_t BNE = (size_t)B_ * N_ * E_;   // 4.19M floats
  const size_t BPE = (size_t)B_ * P_ * E_;   // 2.10M floats

  float* ws   = (float*)d_ws;
  float* kbuf = ws;                // [B*N,E]
  float* vbuf = kbuf + BNE;        // [B*N,E]
  float* qbuf = vbuf + BNE;        // [B*P,E]
  float* tbuf = qbuf + BPE;        // [B*P,N] logits (also hosts partials first)
  float* pout = tbuf;                              // SPLIT*BHP*16 = 8.39M floats
  float* pml  = tbuf + (size_t)SPLIT_ * BHP_ * 16; // SPLIT*BHP*2  = 1.05M floats
  float* abuf = kbuf;              // reuse: attention output (after attn_pass)
  float* mhbuf = vbuf;             // reuse: mh output (after attn_pass)

  // K|V = enc @ [Wk|Wv]
  gemm_kv<<<dim3(256), 256, 0, stream>>>(enc, Wk, Wv, kbuf, vbuf);
  // q = [eln | load] @ Wq_last
  gemm128<<<dim3(128), 256, 0, stream>>>(eln, Wq, load, Wq + 128 * 128, nullptr, qbuf);
  // flash-decoding attention, split over N
  attn_pass<<<dim3(2 * SPLIT_, H_, B_), 256, 0, stream>>>(qbuf, kbuf, vbuf, mask, pout, pml);
  attn_combine<<<dim3(BHP_ / 256), 256, 0, stream>>>(pout, pml, abuf);
  // mh = attn_out @ Wc + bc
  gemm128<<<dim3(128), 256, 0, stream>>>(abuf, Wc, nullptr, nullptr, bc, mhbuf);
  // logits = 10*tanh(mh·encT/sqrt(128)) + mask
  logits_kernel<<<dim3(8, 4, B_), 256, 0, stream>>>(mhbuf, enc, mask, tbuf);
  // probs = softmax(logits/0.1)
  softmax_rows<<<dim3(16384), 256, 0, stream>>>(tbuf, out);
}

// Round 4
// 399.712 us; speedup vs baseline: 1.3720x; 1.2477x over previous
//
#include <hip/hip_runtime.h>
#include <math.h>
#include <stdint.h>

#define B_ 32
#define P_ 512
#define N_ 1024
#define E_ 128
#define H_ 8
#define D_ 16

typedef unsigned short ushort_t;
typedef __attribute__((ext_vector_type(8))) short short8;
typedef __attribute__((ext_vector_type(4))) float f32x4;

union U8 { short8 s8; uint32_t u[4]; };

__device__ __forceinline__ void fma4(float4& acc, float a, float4 w) {
  acc.x = fmaf(a, w.x, acc.x); acc.y = fmaf(a, w.y, acc.y);
  acc.z = fmaf(a, w.z, acc.z); acc.w = fmaf(a, w.w, acc.w);
}
__device__ __forceinline__ void add4(float4& acc, float4 w) {
  acc.x += w.x; acc.y += w.y; acc.z += w.z; acc.w += w.w;
}
__device__ __forceinline__ float fast_tanh(float x) {
  x = fminf(20.f, fmaxf(-20.f, x));
  float e = __expf(2.f * x);
  return (e - 1.f) / (e + 1.f);
}
// float -> interleaved (hi bf16 | lo bf16) dword; lo = exact residual truncated
__device__ __forceinline__ uint32_t f32_to_hl(float x) {
  uint32_t bits = __float_as_uint(x);
  uint32_t hi = bits >> 16;
  float rem = x - __uint_as_float(bits & 0xFFFF0000u);
  uint32_t lo = __float_as_uint(rem) >> 16;
  return hi | (lo << 16);
}

// ---------------------------------------------------------------------------
// Generic fp32 GEMM (kept for Wc): C[M,128] = A[M,128]@W[128,128] (+rank1,+bias)
// ---------------------------------------------------------------------------
__global__ __launch_bounds__(256, 2) void gemm128(
    const float* __restrict__ A, const float* __restrict__ W,
    const float* __restrict__ ea, const float* __restrict__ ew,
    const float* __restrict__ bias, float* __restrict__ C) {
  __shared__ float As[128][33];
  __shared__ float Ws[32][128];
  const int tid = threadIdx.x;
  const size_t m0 = (size_t)blockIdx.x * 128;
  const int tr = tid >> 3, tc = tid & 7;
  const int r0 = tr * 4;
  const int c0 = tc * 16;

  float4 acc[4][4];
#pragma unroll
  for (int j = 0; j < 4; ++j)
#pragma unroll
    for (int i = 0; i < 4; ++i) acc[j][i] = make_float4(0.f, 0.f, 0.f, 0.f);

  for (int kb = 0; kb < 4; ++kb) {
    __syncthreads();
    {
      int idx = tid;
#pragma unroll
      for (int it = 0; it < 4; ++it, idx += 256) {
        int r = idx >> 3, k4 = idx & 7;
        float4 v = reinterpret_cast<const float4*>(A + (m0 + r) * 128 + kb * 32)[k4];
        As[r][k4 * 4 + 0] = v.x; As[r][k4 * 4 + 1] = v.y;
        As[r][k4 * 4 + 2] = v.z; As[r][k4 * 4 + 3] = v.w;
      }
      idx = tid;
#pragma unroll
      for (int it = 0; it < 4; ++it, idx += 256) {
        int kk = idx >> 5, c4 = idx & 31;
        reinterpret_cast<float4*>(&Ws[kk][0])[c4] =
            reinterpret_cast<const float4*>(W + (size_t)(kb * 32 + kk) * 128)[c4];
      }
    }
    __syncthreads();
#pragma unroll 8
    for (int kk = 0; kk < 32; ++kk) {
      float a0 = As[r0 + 0][kk], a1 = As[r0 + 1][kk];
      float a2 = As[r0 + 2][kk], a3 = As[r0 + 3][kk];
      const float4* wr = reinterpret_cast<const float4*>(&Ws[kk][c0]);
      float4 w0 = wr[0], w1 = wr[1], w2 = wr[2], w3 = wr[3];
      fma4(acc[0][0], a0, w0); fma4(acc[0][1], a0, w1); fma4(acc[0][2], a0, w2); fma4(acc[0][3], a0, w3);
      fma4(acc[1][0], a1, w0); fma4(acc[1][1], a1, w1); fma4(acc[1][2], a1, w2); fma4(acc[1][3], a1, w3);
      fma4(acc[2][0], a2, w0); fma4(acc[2][1], a2, w1); fma4(acc[2][2], a2, w2); fma4(acc[2][3], a2, w3);
      fma4(acc[3][0], a3, w0); fma4(acc[3][1], a3, w1); fma4(acc[3][2], a3, w2); fma4(acc[3][3], a3, w3);
    }
  }

  if (ea != nullptr) {
    const float4* ew4 = reinterpret_cast<const float4*>(ew + c0);
    float4 e0 = ew4[0], e1 = ew4[1], e2 = ew4[2], e3 = ew4[3];
#pragma unroll
    for (int j = 0; j < 4; ++j) {
      float av = ea[m0 + r0 + j];
      fma4(acc[j][0], av, e0); fma4(acc[j][1], av, e1);
      fma4(acc[j][2], av, e2); fma4(acc[j][3], av, e3);
    }
  }
  if (bias != nullptr) {
    const float4* b4 = reinterpret_cast<const float4*>(bias + c0);
    float4 b0 = b4[0], b1 = b4[1], b2 = b4[2], b3 = b4[3];
#pragma unroll
    for (int j = 0; j < 4; ++j) {
      add4(acc[j][0], b0); add4(acc[j][1], b1); add4(acc[j][2], b2); add4(acc[j][3], b3);
    }
  }
#pragma unroll
  for (int j = 0; j < 4; ++j) {
    float4* c4p = reinterpret_cast<float4*>(C + (m0 + r0 + j) * 128 + c0);
    c4p[0] = acc[j][0]; c4p[1] = acc[j][1]; c4p[2] = acc[j][2]; c4p[3] = acc[j][3];
  }
}

// ---------------------------------------------------------------------------
// Fused K/V projection -> bf16 hi/lo outputs for MFMA attention.
// khl:  [B*N][256]  (hi,lo) interleaved along d (all 8 heads: 2*col)
// vthl: [B*H*16][2048] V transposed per head: row=(b*8+h)*16+d, el=2*n+part
// ---------------------------------------------------------------------------
__global__ __launch_bounds__(256, 1) void gemm_kv(
    const float* __restrict__ A, const float* __restrict__ Wk,
    const float* __restrict__ Wv, ushort_t* __restrict__ khl,
    ushort_t* __restrict__ vthl) {
  __shared__ float As[128][33];
  __shared__ float Wks[32][128];
  __shared__ float Wvs[32][128];
  const int tid = threadIdx.x;
  const size_t m0 = (size_t)blockIdx.x * 128;
  const int tr = tid >> 3, tc = tid & 7;
  const int r0 = tr * 4;
  const int c0 = tc * 16;

  float4 acck[4][4], accv[4][4];
#pragma unroll
  for (int j = 0; j < 4; ++j)
#pragma unroll
    for (int i = 0; i < 4; ++i) {
      acck[j][i] = make_float4(0.f, 0.f, 0.f, 0.f);
      accv[j][i] = make_float4(0.f, 0.f, 0.f, 0.f);
    }

  for (int kb = 0; kb < 4; ++kb) {
    __syncthreads();
    {
      int idx = tid;
#pragma unroll
      for (int it = 0; it < 4; ++it, idx += 256) {
        int r = idx >> 3, k4 = idx & 7;
        float4 v = reinterpret_cast<const float4*>(A + (m0 + r) * 128 + kb * 32)[k4];
        As[r][k4 * 4 + 0] = v.x; As[r][k4 * 4 + 1] = v.y;
        As[r][k4 * 4 + 2] = v.z; As[r][k4 * 4 + 3] = v.w;
      }
      idx = tid;
#pragma unroll
      for (int it = 0; it < 4; ++it, idx += 256) {
        int kk = idx >> 5, c4 = idx & 31;
        reinterpret_cast<float4*>(&Wks[kk][0])[c4] =
            reinterpret_cast<const float4*>(Wk + (size_t)(kb * 32 + kk) * 128)[c4];
      }
      idx = tid;
#pragma unroll
      for (int it = 0; it < 4; ++it, idx += 256) {
        int kk = idx >> 5, c4 = idx & 31;
        reinterpret_cast<float4*>(&Wvs[kk][0])[c4] =
            reinterpret_cast<const float4*>(Wv + (size_t)(kb * 32 + kk) * 128)[c4];
      }
    }
    __syncthreads();
#pragma unroll 4
    for (int kk = 0; kk < 32; ++kk) {
      float a0 = As[r0 + 0][kk], a1 = As[r0 + 1][kk];
      float a2 = As[r0 + 2][kk], a3 = As[r0 + 3][kk];
      const float4* wkr = reinterpret_cast<const float4*>(&Wks[kk][c0]);
      const float4* wvr = reinterpret_cast<const float4*>(&Wvs[kk][c0]);
#pragma unroll
      for (int i = 0; i < 4; ++i) {
        float4 wk = wkr[i], wv = wvr[i];
        fma4(acck[0][i], a0, wk); fma4(acck[1][i], a1, wk);
        fma4(acck[2][i], a2, wk); fma4(acck[3][i], a3, wk);
        fma4(accv[0][i], a0, wv); fma4(accv[1][i], a1, wv);
        fma4(accv[2][i], a2, wv); fma4(accv[3][i], a3, wv);
      }
    }
  }

  // K epilogue: interleaved hi/lo bf16
#pragma unroll
  for (int j = 0; j < 4; ++j) {
    ushort_t* krow = khl + (m0 + r0 + j) * 256;
#pragma unroll
    for (int i = 0; i < 4; ++i) {
      uint4 pk;
      pk.x = f32_to_hl(acck[j][i].x);
      pk.y = f32_to_hl(acck[j][i].y);
      pk.z = f32_to_hl(acck[j][i].z);
      pk.w = f32_to_hl(acck[j][i].w);
      *reinterpret_cast<uint4*>(krow + 2 * (c0 + 4 * i)) = pk;
    }
  }
  // V epilogue: per-head transposed, interleaved hi/lo along n
  const int bb = (int)(m0 >> 10);
  const int nbase = (int)(m0 & 1023) + r0;   // 4 consecutive n (j=0..3)
#pragma unroll
  for (int i = 0; i < 4; ++i) {
#pragma unroll
    for (int e = 0; e < 4; ++e) {
      const int c = c0 + 4 * i + e;
      const int hh = c >> 4, dd = c & 15;
      uint4 pv;
      pv.x = f32_to_hl(reinterpret_cast<const float*>(&accv[0][i])[e]);
      pv.y = f32_to_hl(reinterpret_cast<const float*>(&accv[1][i])[e]);
      pv.z = f32_to_hl(reinterpret_cast<const float*>(&accv[2][i])[e]);
      pv.w = f32_to_hl(reinterpret_cast<const float*>(&accv[3][i])[e]);
      *reinterpret_cast<uint4*>(
          vthl + (size_t)((bb * H_ + hh) * 16 + dd) * 2048 + 2 * nbase) = pv;
    }
  }
}

// ---------------------------------------------------------------------------
// Q projection: q = [eln | load] @ Wq_last -> qhl [B*P][256] hi/lo interleaved
// ---------------------------------------------------------------------------
__global__ __launch_bounds__(256, 2) void gemm_q(
    const float* __restrict__ A, const float* __restrict__ W,
    const float* __restrict__ ea, const float* __restrict__ ew,
    ushort_t* __restrict__ qhl) {
  __shared__ float As[128][33];
  __shared__ float Ws[32][128];
  const int tid = threadIdx.x;
  const size_t m0 = (size_t)blockIdx.x * 128;
  const int tr = tid >> 3, tc = tid & 7;
  const int r0 = tr * 4;
  const int c0 = tc * 16;

  float4 acc[4][4];
#pragma unroll
  for (int j = 0; j < 4; ++j)
#pragma unroll
    for (int i = 0; i < 4; ++i) acc[j][i] = make_float4(0.f, 0.f, 0.f, 0.f);

  for (int kb = 0; kb < 4; ++kb) {
    __syncthreads();
    {
      int idx = tid;
#pragma unroll
      for (int it = 0; it < 4; ++it, idx += 256) {
        int r = idx >> 3, k4 = idx & 7;
        float4 v = reinterpret_cast<const float4*>(A + (m0 + r) * 128 + kb * 32)[k4];
        As[r][k4 * 4 + 0] = v.x; As[r][k4 * 4 + 1] = v.y;
        As[r][k4 * 4 + 2] = v.z; As[r][k4 * 4 + 3] = v.w;
      }
      idx = tid;
#pragma unroll
      for (int it = 0; it < 4; ++it, idx += 256) {
        int kk = idx >> 5, c4 = idx & 31;
        reinterpret_cast<float4*>(&Ws[kk][0])[c4] =
            reinterpret_cast<const float4*>(W + (size_t)(kb * 32 + kk) * 128)[c4];
      }
    }
    __syncthreads();
#pragma unroll 8
    for (int kk = 0; kk < 32; ++kk) {
      float a0 = As[r0 + 0][kk], a1 = As[r0 + 1][kk];
      float a2 = As[r0 + 2][kk], a3 = As[r0 + 3][kk];
      const float4* wr = reinterpret_cast<const float4*>(&Ws[kk][c0]);
      float4 w0 = wr[0], w1 = wr[1], w2 = wr[2], w3 = wr[3];
      fma4(acc[0][0], a0, w0); fma4(acc[0][1], a0, w1); fma4(acc[0][2], a0, w2); fma4(acc[0][3], a0, w3);
      fma4(acc[1][0], a1, w0); fma4(acc[1][1], a1, w1); fma4(acc[1][2], a1, w2); fma4(acc[1][3], a1, w3);
      fma4(acc[2][0], a2, w0); fma4(acc[2][1], a2, w1); fma4(acc[2][2], a2, w2); fma4(acc[2][3], a2, w3);
      fma4(acc[3][0], a3, w0); fma4(acc[3][1], a3, w1); fma4(acc[3][2], a3, w2); fma4(acc[3][3], a3, w3);
    }
  }

  {
    const float4* ew4 = reinterpret_cast<const float4*>(ew + c0);
    float4 e0 = ew4[0], e1 = ew4[1], e2 = ew4[2], e3 = ew4[3];
#pragma unroll
    for (int j = 0; j < 4; ++j) {
      float av = ea[m0 + r0 + j];
      fma4(acc[j][0], av, e0); fma4(acc[j][1], av, e1);
      fma4(acc[j][2], av, e2); fma4(acc[j][3], av, e3);
    }
  }
#pragma unroll
  for (int j = 0; j < 4; ++j) {
    ushort_t* qrow = qhl + (m0 + r0 + j) * 256;
#pragma unroll
    for (int i = 0; i < 4; ++i) {
      uint4 pq;
      pq.x = f32_to_hl(acc[j][i].x);
      pq.y = f32_to_hl(acc[j][i].y);
      pq.z = f32_to_hl(acc[j][i].z);
      pq.w = f32_to_hl(acc[j][i].w);
      *reinterpret_cast<uint4*>(qrow + 2 * (c0 + 4 * i)) = pq;
    }
  }
}

// ---------------------------------------------------------------------------
// MFMA flash attention. Block = (b, h, 64 p-rows), 4 waves, wave = 16 p.
// S^T = K·Q^T via mfma_16x16x32 with (hi,lo) packed in K-dim; softmax lane-
// local (col=lane&15 = p); P^T feeds O^T = V^T·P^T directly (B-layout match).
// ---------------------------------------------------------------------------
__global__ __launch_bounds__(256, 4) void attn_mfma(
    const ushort_t* __restrict__ qhl, const ushort_t* __restrict__ khl,
    const ushort_t* __restrict__ vthl, const float* __restrict__ mask,
    float* __restrict__ O) {
  const int b = blockIdx.z, h = blockIdx.y, pt = blockIdx.x;
  const int tid = threadIdx.x;
  const int w = tid >> 6, lane = tid & 63;
  const int lp = lane & 15, g = lane >> 4;
  const int p = pt * 64 + w * 16 + lp;

  __shared__ __align__(16) ushort_t Ks[64 * 40];    // row stride 40 el (80 B)
  __shared__ __align__(16) ushort_t VTs[16 * 136];  // row stride 136 el (272 B)

  // Q fragments: B1 = (qh,qh) pairs, B2 = (ql,0) pairs
  uint4 qld = *reinterpret_cast<const uint4*>(
      qhl + (size_t)(b * P_ + p) * 256 + h * 32 + g * 8);
  U8 qb1u, qb2u;
  {
    uint32_t qa[4] = {qld.x, qld.y, qld.z, qld.w};
#pragma unroll
    for (int i = 0; i < 4; ++i) {
      uint32_t lo16 = qa[i] & 0xFFFFu;
      qb1u.u[i] = lo16 | (lo16 << 16);
      qb2u.u[i] = qa[i] >> 16;
    }
  }
  const short8 qb1 = qb1u.s8, qb2 = qb2u.s8;

  const float* mrow = mask + (size_t)(b * P_ + p) * N_;

  f32x4 acc_o = {0.f, 0.f, 0.f, 0.f};
  float m_run = -1e30f, l_run = 0.f;

  for (int ch = 0; ch < N_ / 64; ++ch) {
    const int n0 = ch * 64;
    __syncthreads();
    {
      const int n = tid >> 2, seg = tid & 3;
      uint4 kv = *reinterpret_cast<const uint4*>(
          khl + (size_t)(b * N_ + n0 + n) * 256 + h * 32 + seg * 8);
      *reinterpret_cast<uint4*>(Ks + n * 40 + seg * 8) = kv;
      const int d = tid >> 4, s2 = tid & 15;
      uint4 vv = *reinterpret_cast<const uint4*>(
          vthl + (size_t)((b * H_ + h) * 16 + d) * 2048 + n0 * 2 + s2 * 8);
      *reinterpret_cast<uint4*>(VTs + d * 136 + s2 * 8) = vv;
    }
    __syncthreads();

    // scores: S^T tiles (lane holds 4 n-values for its p)
    float sv[4][4];
    float cmax = -1e30f;
#pragma unroll
    for (int tt = 0; tt < 4; ++tt) {
      short8 ka = *reinterpret_cast<const short8*>(Ks + (tt * 16 + lp) * 40 + g * 8);
      f32x4 a = {0.f, 0.f, 0.f, 0.f};
      a = __builtin_amdgcn_mfma_f32_16x16x32_bf16(ka, qb1, a, 0, 0, 0);
      a = __builtin_amdgcn_mfma_f32_16x16x32_bf16(ka, qb2, a, 0, 0, 0);
      float4 mv = *reinterpret_cast<const float4*>(mrow + n0 + tt * 16 + g * 4);
      sv[tt][0] = fmaf(a[0], 0.25f, mv.x);
      sv[tt][1] = fmaf(a[1], 0.25f, mv.y);
      sv[tt][2] = fmaf(a[2], 0.25f, mv.z);
      sv[tt][3] = fmaf(a[3], 0.25f, mv.w);
      cmax = fmaxf(cmax, fmaxf(fmaxf(sv[tt][0], sv[tt][1]), fmaxf(sv[tt][2], sv[tt][3])));
    }
    cmax = fmaxf(cmax, __shfl_xor(cmax, 16));
    cmax = fmaxf(cmax, __shfl_xor(cmax, 32));
    const float nm = fmaxf(m_run, cmax);
    const float f = __expf(m_run - nm);
    acc_o[0] *= f; acc_o[1] *= f; acc_o[2] *= f; acc_o[3] *= f;
    float ls = 0.f;
#pragma unroll
    for (int tt = 0; tt < 4; ++tt)
#pragma unroll
      for (int r = 0; r < 4; ++r) {
        float e = __expf(sv[tt][r] - nm);
        sv[tt][r] = e;
        ls += e;
      }
    ls += __shfl_xor(ls, 16);
    ls += __shfl_xor(ls, 32);
    l_run = l_run * f + ls;
    m_run = nm;

    // PV: O^T += V^T · P^T   (P packed hi/lo into K-dim pairs)
#pragma unroll
    for (int tt = 0; tt < 4; ++tt) {
      U8 pb1, pb2;
#pragma unroll
      for (int r = 0; r < 4; ++r) {
        float pv = sv[tt][r];
        uint32_t bits = __float_as_uint(pv);
        uint32_t h16 = bits >> 16;
        float rem = pv - __uint_as_float(bits & 0xFFFF0000u);
        pb1.u[r] = h16 | (h16 << 16);
        pb2.u[r] = __float_as_uint(rem) >> 16;
      }
      short8 va = *reinterpret_cast<const short8*>(VTs + lp * 136 + tt * 32 + g * 8);
      acc_o = __builtin_amdgcn_mfma_f32_16x16x32_bf16(va, pb1.s8, acc_o, 0, 0, 0);
      acc_o = __builtin_amdgcn_mfma_f32_16x16x32_bf16(va, pb2.s8, acc_o, 0, 0, 0);
    }
  }

  const float inv = 1.f / l_run;
  float4 o;
  o.x = acc_o[0] * inv; o.y = acc_o[1] * inv;
  o.z = acc_o[2] * inv; o.w = acc_o[3] * inv;
  *reinterpret_cast<float4*>(O + (size_t)(b * P_ + p) * E_ + h * 16 + g * 4) = o;
}

// ---------------------------------------------------------------------------
// T[b,p,n] = 10*tanh((mh[b,p,:]·enc[b,n,:])/sqrt(128)) + mask[b,p,n]
// ---------------------------------------------------------------------------
__global__ __launch_bounds__(256, 2) void logits_kernel(
    const float* __restrict__ mh, const float* __restrict__ enc,
    const float* __restrict__ mask, float* __restrict__ T) {
  const int b = blockIdx.z;
  const int p0 = blockIdx.y * 128;
  const int n0 = blockIdx.x * 128;
  __shared__ float As[128][33];
  __shared__ float Bs[32][132];
  const int tid = threadIdx.x;
  const int tr = tid >> 3, tc = tid & 7;
  const int r0 = tr * 4, c0 = tc * 16;
  const float* Ab = mh + ((size_t)b * P_ + p0) * E_;
  const float* Eb = enc + (size_t)b * N_ * E_;

  float4 acc[4][4];
#pragma unroll
  for (int j = 0; j < 4; ++j)
#pragma unroll
    for (int i = 0; i < 4; ++i) acc[j][i] = make_float4(0.f, 0.f, 0.f, 0.f);

  for (int kb = 0; kb < 4; ++kb) {
    __syncthreads();
    int idx = tid;
#pragma unroll
    for (int it = 0; it < 4; ++it, idx += 256) {
      int r = idx >> 3, k4 = idx & 7;
      float4 v = reinterpret_cast<const float4*>(Ab + (size_t)r * 128 + kb * 32)[k4];
      As[r][k4 * 4 + 0] = v.x; As[r][k4 * 4 + 1] = v.y;
      As[r][k4 * 4 + 2] = v.z; As[r][k4 * 4 + 3] = v.w;
    }
    idx = tid;
#pragma unroll
    for (int it = 0; it < 4; ++it, idx += 256) {
      int nn = idx >> 3, k4 = idx & 7;
      float4 v = reinterpret_cast<const float4*>(Eb + (size_t)(n0 + nn) * 128 + kb * 32)[k4];
      Bs[k4 * 4 + 0][nn] = v.x; Bs[k4 * 4 + 1][nn] = v.y;
      Bs[k4 * 4 + 2][nn] = v.z; Bs[k4 * 4 + 3][nn] = v.w;
    }
    __syncthreads();
#pragma unroll 8
    for (int kk = 0; kk < 32; ++kk) {
      float a0 = As[r0 + 0][kk], a1 = As[r0 + 1][kk];
      float a2 = As[r0 + 2][kk], a3 = As[r0 + 3][kk];
      const float4* br = reinterpret_cast<const float4*>(&Bs[kk][c0]);
      float4 w0 = br[0], w1 = br[1], w2 = br[2], w3 = br[3];
      fma4(acc[0][0], a0, w0); fma4(acc[0][1], a0, w1); fma4(acc[0][2], a0, w2); fma4(acc[0][3], a0, w3);
      fma4(acc[1][0], a1, w0); fma4(acc[1][1], a1, w1); fma4(acc[1][2], a1, w2); fma4(acc[1][3], a1, w3);
      fma4(acc[2][0], a2, w0); fma4(acc[2][1], a2, w1); fma4(acc[2][2], a2, w2); fma4(acc[2][3], a2, w3);
      fma4(acc[3][0], a3, w0); fma4(acc[3][1], a3, w1); fma4(acc[3][2], a3, w2); fma4(acc[3][3], a3, w3);
    }
  }

  const float inv_s = 0.08838834764831845f;  // 1/sqrt(128)
#pragma unroll
  for (int j = 0; j < 4; ++j) {
    const size_t prow = ((size_t)b * P_ + p0 + r0 + j) * N_ + n0 + c0;
    const float4* mk4 = reinterpret_cast<const float4*>(mask + prow);
    float4* t4 = reinterpret_cast<float4*>(T + prow);
#pragma unroll
    for (int i = 0; i < 4; ++i) {
      float4 a = acc[j][i];
      float4 mv = mk4[i];
      float4 o;
      o.x = fmaf(10.f, fast_tanh(a.x * inv_s), mv.x);
      o.y = fmaf(10.f, fast_tanh(a.y * inv_s), mv.y);
      o.z = fmaf(10.f, fast_tanh(a.z * inv_s), mv.z);
      o.w = fmaf(10.f, fast_tanh(a.w * inv_s), mv.w);
      t4[i] = o;
    }
  }
}

// ---------------------------------------------------------------------------
// probs[row,:] = softmax(T[row,:] * 10)
// ---------------------------------------------------------------------------
__global__ __launch_bounds__(256, 4) void softmax_rows(
    const float* __restrict__ T, float* __restrict__ O) {
  const size_t row = blockIdx.x;
  const int tid = threadIdx.x;
  const float4 v = reinterpret_cast<const float4*>(T + row * N_)[tid];
  float lm = fmaxf(fmaxf(v.x, v.y), fmaxf(v.z, v.w));
#pragma unroll
  for (int o = 32; o; o >>= 1) lm = fmaxf(lm, __shfl_xor(lm, o));
  __shared__ float red[8];
  const int wave = tid >> 6, lane = tid & 63;
  if (lane == 0) red[wave] = lm;
  __syncthreads();
  const float m = fmaxf(fmaxf(red[0], red[1]), fmaxf(red[2], red[3]));
  float4 w;
  w.x = __expf((v.x - m) * 10.f);
  w.y = __expf((v.y - m) * 10.f);
  w.z = __expf((v.z - m) * 10.f);
  w.w = __expf((v.w - m) * 10.f);
  float ls = w.x + w.y + w.z + w.w;
#pragma unroll
  for (int o = 32; o; o >>= 1) ls += __shfl_xor(ls, o);
  if (lane == 0) red[4 + wave] = ls;
  __syncthreads();
  const float inv = 1.f / (red[4] + red[5] + red[6] + red[7]);
  float4 o4;
  o4.x = w.x * inv; o4.y = w.y * inv; o4.z = w.z * inv; o4.w = w.w * inv;
  reinterpret_cast<float4*>(O + row * N_)[tid] = o4;
}

extern "C" void kernel_launch(void* const* d_in, const int* in_sizes, int n_in,
                              void* d_out, int out_size, void* d_ws, size_t ws_size,
                              hipStream_t stream) {
  const float* eln  = (const float*)d_in[0];
  const float* load = (const float*)d_in[1];
  const float* mask = (const float*)d_in[2];
  const float* enc  = (const float*)d_in[3];
  const float* Wq   = (const float*)d_in[4];
  const float* Wk   = (const float*)d_in[5];
  const float* Wv   = (const float*)d_in[6];
  const float* Wc   = (const float*)d_in[7];
  const float* bc   = (const float*)d_in[8];
  float* out = (float*)d_out;

  // Workspace layout (bytes):
  //   khl  : 32768*256*2 = 16.78 MB   (bf16 hi/lo interleaved K)
  //   vthl :  4096*2048*2 = 16.78 MB  (bf16 hi/lo V^T per head)
  //   qhl  : 16384*256*2 =  8.39 MB   (bf16 hi/lo Q) -- reused as mhbuf (fp32)
  //   tbuf : 16384*1024*4 = 67.11 MB  (logits)  -- abuf (fp32, 8.39 MB) at head
  char* base = (char*)d_ws;
  ushort_t* khl  = (ushort_t*)base;
  ushort_t* vthl = (ushort_t*)(base + 16777216);
  ushort_t* qhl  = (ushort_t*)(base + 2 * 16777216);
  float* mhbuf   = (float*)(base + 2 * 16777216);            // overlaps qhl
  float* tbuf    = (float*)(base + 2 * 16777216 + 8388608);
  float* abuf    = tbuf;                                     // dead before logits

  // K|V projections -> bf16 hi/lo (+ V transpose)
  gemm_kv<<<dim3(256), 256, 0, stream>>>(enc, Wk, Wv, khl, vthl);
  // q = [eln | load] @ Wq_last -> bf16 hi/lo
  gemm_q<<<dim3(128), 256, 0, stream>>>(eln, Wq, load, Wq + 128 * 128, qhl);
  // MFMA flash attention
  attn_mfma<<<dim3(P_ / 64, H_, B_), 256, 0, stream>>>(qhl, khl, vthl, mask, abuf);
  // mh = attn_out @ Wc + bc   (writes over qhl region; qhl is dead)
  gemm128<<<dim3(128), 256, 0, stream>>>(abuf, Wc, nullptr, nullptr, bc, mhbuf);
  // logits = 10*tanh(mh·encT/sqrt(128)) + mask  (overwrites abuf region)
  logits_kernel<<<dim3(8, 4, B_), 256, 0, stream>>>(mhbuf, enc, mask, tbuf);
  // probs = softmax(logits/0.1)
  softmax_rows<<<dim3(16384), 256, 0, stream>>>(tbuf, out);
}

// Round 5
// 357.559 us; speedup vs baseline: 1.5338x; 1.1179x over previous
//
#include <hip/hip_runtime.h>
#include <math.h>
#include <stdint.h>

#define B_ 32
#define P_ 512
#define N_ 1024
#define E_ 128
#define H_ 8
#define D_ 16

typedef unsigned short ushort_t;
typedef __attribute__((ext_vector_type(8))) short short8;
typedef __attribute__((ext_vector_type(4))) float f32x4;

union U8 { short8 s8; uint32_t u[4]; };

__device__ __forceinline__ void fma4(float4& acc, float a, float4 w) {
  acc.x = fmaf(a, w.x, acc.x); acc.y = fmaf(a, w.y, acc.y);
  acc.z = fmaf(a, w.z, acc.z); acc.w = fmaf(a, w.w, acc.w);
}
__device__ __forceinline__ void add4(float4& acc, float4 w) {
  acc.x += w.x; acc.y += w.y; acc.z += w.z; acc.w += w.w;
}
__device__ __forceinline__ float fast_tanh(float x) {
  x = fminf(20.f, fmaxf(-20.f, x));
  float e = __expf(2.f * x);
  return (e - 1.f) / (e + 1.f);
}
// float -> interleaved (hi bf16 | lo bf16) dword; lo = exact residual truncated
__device__ __forceinline__ uint32_t f32_to_hl(float x) {
  uint32_t bits = __float_as_uint(x);
  uint32_t hi = bits >> 16;
  float rem = x - __uint_as_float(bits & 0xFFFF0000u);
  uint32_t lo = __float_as_uint(rem) >> 16;
  return hi | (lo << 16);
}

// ---------------------------------------------------------------------------
// Generic fp32 GEMM (kept for Wc): C[M,128] = A[M,128]@W[128,128] (+rank1,+bias)
// ---------------------------------------------------------------------------
__global__ __launch_bounds__(256, 2) void gemm128(
    const float* __restrict__ A, const float* __restrict__ W,
    const float* __restrict__ ea, const float* __restrict__ ew,
    const float* __restrict__ bias, float* __restrict__ C) {
  __shared__ float As[128][33];
  __shared__ float Ws[32][128];
  const int tid = threadIdx.x;
  const size_t m0 = (size_t)blockIdx.x * 128;
  const int tr = tid >> 3, tc = tid & 7;
  const int r0 = tr * 4;
  const int c0 = tc * 16;

  float4 acc[4][4];
#pragma unroll
  for (int j = 0; j < 4; ++j)
#pragma unroll
    for (int i = 0; i < 4; ++i) acc[j][i] = make_float4(0.f, 0.f, 0.f, 0.f);

  for (int kb = 0; kb < 4; ++kb) {
    __syncthreads();
    {
      int idx = tid;
#pragma unroll
      for (int it = 0; it < 4; ++it, idx += 256) {
        int r = idx >> 3, k4 = idx & 7;
        float4 v = reinterpret_cast<const float4*>(A + (m0 + r) * 128 + kb * 32)[k4];
        As[r][k4 * 4 + 0] = v.x; As[r][k4 * 4 + 1] = v.y;
        As[r][k4 * 4 + 2] = v.z; As[r][k4 * 4 + 3] = v.w;
      }
      idx = tid;
#pragma unroll
      for (int it = 0; it < 4; ++it, idx += 256) {
        int kk = idx >> 5, c4 = idx & 31;
        reinterpret_cast<float4*>(&Ws[kk][0])[c4] =
            reinterpret_cast<const float4*>(W + (size_t)(kb * 32 + kk) * 128)[c4];
      }
    }
    __syncthreads();
#pragma unroll 8
    for (int kk = 0; kk < 32; ++kk) {
      float a0 = As[r0 + 0][kk], a1 = As[r0 + 1][kk];
      float a2 = As[r0 + 2][kk], a3 = As[r0 + 3][kk];
      const float4* wr = reinterpret_cast<const float4*>(&Ws[kk][c0]);
      float4 w0 = wr[0], w1 = wr[1], w2 = wr[2], w3 = wr[3];
      fma4(acc[0][0], a0, w0); fma4(acc[0][1], a0, w1); fma4(acc[0][2], a0, w2); fma4(acc[0][3], a0, w3);
      fma4(acc[1][0], a1, w0); fma4(acc[1][1], a1, w1); fma4(acc[1][2], a1, w2); fma4(acc[1][3], a1, w3);
      fma4(acc[2][0], a2, w0); fma4(acc[2][1], a2, w1); fma4(acc[2][2], a2, w2); fma4(acc[2][3], a2, w3);
      fma4(acc[3][0], a3, w0); fma4(acc[3][1], a3, w1); fma4(acc[3][2], a3, w2); fma4(acc[3][3], a3, w3);
    }
  }

  if (ea != nullptr) {
    const float4* ew4 = reinterpret_cast<const float4*>(ew + c0);
    float4 e0 = ew4[0], e1 = ew4[1], e2 = ew4[2], e3 = ew4[3];
#pragma unroll
    for (int j = 0; j < 4; ++j) {
      float av = ea[m0 + r0 + j];
      fma4(acc[j][0], av, e0); fma4(acc[j][1], av, e1);
      fma4(acc[j][2], av, e2); fma4(acc[j][3], av, e3);
    }
  }
  if (bias != nullptr) {
    const float4* b4 = reinterpret_cast<const float4*>(bias + c0);
    float4 b0 = b4[0], b1 = b4[1], b2 = b4[2], b3 = b4[3];
#pragma unroll
    for (int j = 0; j < 4; ++j) {
      add4(acc[j][0], b0); add4(acc[j][1], b1); add4(acc[j][2], b2); add4(acc[j][3], b3);
    }
  }
#pragma unroll
  for (int j = 0; j < 4; ++j) {
    float4* c4p = reinterpret_cast<float4*>(C + (m0 + r0 + j) * 128 + c0);
    c4p[0] = acc[j][0]; c4p[1] = acc[j][1]; c4p[2] = acc[j][2]; c4p[3] = acc[j][3];
  }
}

// ---------------------------------------------------------------------------
// Fused K/V projection -> bf16 hi/lo outputs for MFMA attention.
// khl:  [B*N][256]  (hi,lo) interleaved along d (all 8 heads: 2*col)
// vthl: [B*H*16][2048] V transposed per head: row=(b*8+h)*16+d, el=2*n+part
// ---------------------------------------------------------------------------
__global__ __launch_bounds__(256, 1) void gemm_kv(
    const float* __restrict__ A, const float* __restrict__ Wk,
    const float* __restrict__ Wv, ushort_t* __restrict__ khl,
    ushort_t* __restrict__ vthl) {
  __shared__ float As[128][33];
  __shared__ float Wks[32][128];
  __shared__ float Wvs[32][128];
  const int tid = threadIdx.x;
  const size_t m0 = (size_t)blockIdx.x * 128;
  const int tr = tid >> 3, tc = tid & 7;
  const int r0 = tr * 4;
  const int c0 = tc * 16;

  float4 acck[4][4], accv[4][4];
#pragma unroll
  for (int j = 0; j < 4; ++j)
#pragma unroll
    for (int i = 0; i < 4; ++i) {
      acck[j][i] = make_float4(0.f, 0.f, 0.f, 0.f);
      accv[j][i] = make_float4(0.f, 0.f, 0.f, 0.f);
    }

  for (int kb = 0; kb < 4; ++kb) {
    __syncthreads();
    {
      int idx = tid;
#pragma unroll
      for (int it = 0; it < 4; ++it, idx += 256) {
        int r = idx >> 3, k4 = idx & 7;
        float4 v = reinterpret_cast<const float4*>(A + (m0 + r) * 128 + kb * 32)[k4];
        As[r][k4 * 4 + 0] = v.x; As[r][k4 * 4 + 1] = v.y;
        As[r][k4 * 4 + 2] = v.z; As[r][k4 * 4 + 3] = v.w;
      }
      idx = tid;
#pragma unroll
      for (int it = 0; it < 4; ++it, idx += 256) {
        int kk = idx >> 5, c4 = idx & 31;
        reinterpret_cast<float4*>(&Wks[kk][0])[c4] =
            reinterpret_cast<const float4*>(Wk + (size_t)(kb * 32 + kk) * 128)[c4];
      }
      idx = tid;
#pragma unroll
      for (int it = 0; it < 4; ++it, idx += 256) {
        int kk = idx >> 5, c4 = idx & 31;
        reinterpret_cast<float4*>(&Wvs[kk][0])[c4] =
            reinterpret_cast<const float4*>(Wv + (size_t)(kb * 32 + kk) * 128)[c4];
      }
    }
    __syncthreads();
#pragma unroll 4
    for (int kk = 0; kk < 32; ++kk) {
      float a0 = As[r0 + 0][kk], a1 = As[r0 + 1][kk];
      float a2 = As[r0 + 2][kk], a3 = As[r0 + 3][kk];
      const float4* wkr = reinterpret_cast<const float4*>(&Wks[kk][c0]);
      const float4* wvr = reinterpret_cast<const float4*>(&Wvs[kk][c0]);
#pragma unroll
      for (int i = 0; i < 4; ++i) {
        float4 wk = wkr[i], wv = wvr[i];
        fma4(acck[0][i], a0, wk); fma4(acck[1][i], a1, wk);
        fma4(acck[2][i], a2, wk); fma4(acck[3][i], a3, wk);
        fma4(accv[0][i], a0, wv); fma4(accv[1][i], a1, wv);
        fma4(accv[2][i], a2, wv); fma4(accv[3][i], a3, wv);
      }
    }
  }

  // K epilogue: interleaved hi/lo bf16
#pragma unroll
  for (int j = 0; j < 4; ++j) {
    ushort_t* krow = khl + (m0 + r0 + j) * 256;
#pragma unroll
    for (int i = 0; i < 4; ++i) {
      uint4 pk;
      pk.x = f32_to_hl(acck[j][i].x);
      pk.y = f32_to_hl(acck[j][i].y);
      pk.z = f32_to_hl(acck[j][i].z);
      pk.w = f32_to_hl(acck[j][i].w);
      *reinterpret_cast<uint4*>(krow + 2 * (c0 + 4 * i)) = pk;
    }
  }
  // V epilogue: per-head transposed, interleaved hi/lo along n
  const int bb = (int)(m0 >> 10);
  const int nbase = (int)(m0 & 1023) + r0;   // 4 consecutive n (j=0..3)
#pragma unroll
  for (int i = 0; i < 4; ++i) {
#pragma unroll
    for (int e = 0; e < 4; ++e) {
      const int c = c0 + 4 * i + e;
      const int hh = c >> 4, dd = c & 15;
      uint4 pv;
      pv.x = f32_to_hl(reinterpret_cast<const float*>(&accv[0][i])[e]);
      pv.y = f32_to_hl(reinterpret_cast<const float*>(&accv[1][i])[e]);
      pv.z = f32_to_hl(reinterpret_cast<const float*>(&accv[2][i])[e]);
      pv.w = f32_to_hl(reinterpret_cast<const float*>(&accv[3][i])[e]);
      *reinterpret_cast<uint4*>(
          vthl + (size_t)((bb * H_ + hh) * 16 + dd) * 2048 + 2 * nbase) = pv;
    }
  }
}

// ---------------------------------------------------------------------------
// Q projection: q = [eln | load] @ Wq_last -> qhl [B*P][256] hi/lo interleaved
// ---------------------------------------------------------------------------
__global__ __launch_bounds__(256, 2) void gemm_q(
    const float* __restrict__ A, const float* __restrict__ W,
    const float* __restrict__ ea, const float* __restrict__ ew,
    ushort_t* __restrict__ qhl) {
  __shared__ float As[128][33];
  __shared__ float Ws[32][128];
  const int tid = threadIdx.x;
  const size_t m0 = (size_t)blockIdx.x * 128;
  const int tr = tid >> 3, tc = tid & 7;
  const int r0 = tr * 4;
  const int c0 = tc * 16;

  float4 acc[4][4];
#pragma unroll
  for (int j = 0; j < 4; ++j)
#pragma unroll
    for (int i = 0; i < 4; ++i) acc[j][i] = make_float4(0.f, 0.f, 0.f, 0.f);

  for (int kb = 0; kb < 4; ++kb) {
    __syncthreads();
    {
      int idx = tid;
#pragma unroll
      for (int it = 0; it < 4; ++it, idx += 256) {
        int r = idx >> 3, k4 = idx & 7;
        float4 v = reinterpret_cast<const float4*>(A + (m0 + r) * 128 + kb * 32)[k4];
        As[r][k4 * 4 + 0] = v.x; As[r][k4 * 4 + 1] = v.y;
        As[r][k4 * 4 + 2] = v.z; As[r][k4 * 4 + 3] = v.w;
      }
      idx = tid;
#pragma unroll
      for (int it = 0; it < 4; ++it, idx += 256) {
        int kk = idx >> 5, c4 = idx & 31;
        reinterpret_cast<float4*>(&Ws[kk][0])[c4] =
            reinterpret_cast<const float4*>(W + (size_t)(kb * 32 + kk) * 128)[c4];
      }
    }
    __syncthreads();
#pragma unroll 8
    for (int kk = 0; kk < 32; ++kk) {
      float a0 = As[r0 + 0][kk], a1 = As[r0 + 1][kk];
      float a2 = As[r0 + 2][kk], a3 = As[r0 + 3][kk];
      const float4* wr = reinterpret_cast<const float4*>(&Ws[kk][c0]);
      float4 w0 = wr[0], w1 = wr[1], w2 = wr[2], w3 = wr[3];
      fma4(acc[0][0], a0, w0); fma4(acc[0][1], a0, w1); fma4(acc[0][2], a0, w2); fma4(acc[0][3], a0, w3);
      fma4(acc[1][0], a1, w0); fma4(acc[1][1], a1, w1); fma4(acc[1][2], a1, w2); fma4(acc[1][3], a1, w3);
      fma4(acc[2][0], a2, w0); fma4(acc[2][1], a2, w1); fma4(acc[2][2], a2, w2); fma4(acc[2][3], a2, w3);
      fma4(acc[3][0], a3, w0); fma4(acc[3][1], a3, w1); fma4(acc[3][2], a3, w2); fma4(acc[3][3], a3, w3);
    }
  }

  {
    const float4* ew4 = reinterpret_cast<const float4*>(ew + c0);
    float4 e0 = ew4[0], e1 = ew4[1], e2 = ew4[2], e3 = ew4[3];
#pragma unroll
    for (int j = 0; j < 4; ++j) {
      float av = ea[m0 + r0 + j];
      fma4(acc[j][0], av, e0); fma4(acc[j][1], av, e1);
      fma4(acc[j][2], av, e2); fma4(acc[j][3], av, e3);
    }
  }
#pragma unroll
  for (int j = 0; j < 4; ++j) {
    ushort_t* qrow = qhl + (m0 + r0 + j) * 256;
#pragma unroll
    for (int i = 0; i < 4; ++i) {
      uint4 pq;
      pq.x = f32_to_hl(acc[j][i].x);
      pq.y = f32_to_hl(acc[j][i].y);
      pq.z = f32_to_hl(acc[j][i].z);
      pq.w = f32_to_hl(acc[j][i].w);
      *reinterpret_cast<uint4*>(qrow + 2 * (c0 + 4 * i)) = pq;
    }
  }
}

// ---------------------------------------------------------------------------
// MFMA flash attention, 2 p-tiles per wave (ILP x2, halved staging per p).
// Block = (b, h, 128 p-rows), 4 waves; wave owns p and p+64.
// ---------------------------------------------------------------------------
__global__ __launch_bounds__(256, 4) void attn_mfma(
    const ushort_t* __restrict__ qhl, const ushort_t* __restrict__ khl,
    const ushort_t* __restrict__ vthl, const float* __restrict__ mask,
    float* __restrict__ O) {
  const int b = blockIdx.z, h = blockIdx.y, pt = blockIdx.x;
  const int tid = threadIdx.x;
  const int w = tid >> 6, lane = tid & 63;
  const int lp = lane & 15, g = lane >> 4;
  const int pA = pt * 128 + w * 16 + lp;
  const int pB = pA + 64;

  __shared__ __align__(16) ushort_t Ks[64 * 40];    // row stride 40 el (80 B)
  __shared__ __align__(16) ushort_t VTs[16 * 136];  // row stride 136 el (272 B)

  // Q fragments for both p-tiles: B1 = (qh,qh) pairs, B2 = (ql,0) pairs
  U8 qA1u, qA2u, qB1u, qB2u;
  {
    uint4 qldA = *reinterpret_cast<const uint4*>(
        qhl + (size_t)(b * P_ + pA) * 256 + h * 32 + g * 8);
    uint4 qldB = *reinterpret_cast<const uint4*>(
        qhl + (size_t)(b * P_ + pB) * 256 + h * 32 + g * 8);
    uint32_t a[4] = {qldA.x, qldA.y, qldA.z, qldA.w};
    uint32_t c[4] = {qldB.x, qldB.y, qldB.z, qldB.w};
#pragma unroll
    for (int i = 0; i < 4; ++i) {
      uint32_t lo16 = a[i] & 0xFFFFu;
      qA1u.u[i] = lo16 | (lo16 << 16);
      qA2u.u[i] = a[i] >> 16;
      uint32_t lo16b = c[i] & 0xFFFFu;
      qB1u.u[i] = lo16b | (lo16b << 16);
      qB2u.u[i] = c[i] >> 16;
    }
  }
  const short8 qA1 = qA1u.s8, qA2 = qA2u.s8, qB1 = qB1u.s8, qB2 = qB2u.s8;

  const float* mrowA = mask + (size_t)(b * P_ + pA) * N_;
  const float* mrowB = mask + (size_t)(b * P_ + pB) * N_;

  f32x4 accA = {0.f, 0.f, 0.f, 0.f}, accB = {0.f, 0.f, 0.f, 0.f};
  float mA = -1e30f, lA = 0.f, mB = -1e30f, lB = 0.f;

  for (int ch = 0; ch < N_ / 64; ++ch) {
    const int n0 = ch * 64;
    __syncthreads();
    {
      const int n = tid >> 2, seg = tid & 3;
      uint4 kv = *reinterpret_cast<const uint4*>(
          khl + (size_t)(b * N_ + n0 + n) * 256 + h * 32 + seg * 8);
      *reinterpret_cast<uint4*>(Ks + n * 40 + seg * 8) = kv;
      const int d = tid >> 4, s2 = tid & 15;
      uint4 vv = *reinterpret_cast<const uint4*>(
          vthl + (size_t)((b * H_ + h) * 16 + d) * 2048 + n0 * 2 + s2 * 8);
      *reinterpret_cast<uint4*>(VTs + d * 136 + s2 * 8) = vv;
    }
    __syncthreads();

    // scores for both p-tiles; K fragment loaded once, used twice
    float svA[4][4], svB[4][4];
    float cmA = -1e30f, cmB = -1e30f;
#pragma unroll
    for (int tt = 0; tt < 4; ++tt) {
      short8 ka = *reinterpret_cast<const short8*>(Ks + (tt * 16 + lp) * 40 + g * 8);
      f32x4 aA = {0.f, 0.f, 0.f, 0.f};
      aA = __builtin_amdgcn_mfma_f32_16x16x32_bf16(ka, qA1, aA, 0, 0, 0);
      aA = __builtin_amdgcn_mfma_f32_16x16x32_bf16(ka, qA2, aA, 0, 0, 0);
      f32x4 aB = {0.f, 0.f, 0.f, 0.f};
      aB = __builtin_amdgcn_mfma_f32_16x16x32_bf16(ka, qB1, aB, 0, 0, 0);
      aB = __builtin_amdgcn_mfma_f32_16x16x32_bf16(ka, qB2, aB, 0, 0, 0);
      float4 mvA = *reinterpret_cast<const float4*>(mrowA + n0 + tt * 16 + g * 4);
      float4 mvB = *reinterpret_cast<const float4*>(mrowB + n0 + tt * 16 + g * 4);
      svA[tt][0] = fmaf(aA[0], 0.25f, mvA.x);
      svA[tt][1] = fmaf(aA[1], 0.25f, mvA.y);
      svA[tt][2] = fmaf(aA[2], 0.25f, mvA.z);
      svA[tt][3] = fmaf(aA[3], 0.25f, mvA.w);
      svB[tt][0] = fmaf(aB[0], 0.25f, mvB.x);
      svB[tt][1] = fmaf(aB[1], 0.25f, mvB.y);
      svB[tt][2] = fmaf(aB[2], 0.25f, mvB.z);
      svB[tt][3] = fmaf(aB[3], 0.25f, mvB.w);
      cmA = fmaxf(cmA, fmaxf(fmaxf(svA[tt][0], svA[tt][1]), fmaxf(svA[tt][2], svA[tt][3])));
      cmB = fmaxf(cmB, fmaxf(fmaxf(svB[tt][0], svB[tt][1]), fmaxf(svB[tt][2], svB[tt][3])));
    }
    cmA = fmaxf(cmA, __shfl_xor(cmA, 16));
    cmB = fmaxf(cmB, __shfl_xor(cmB, 16));
    cmA = fmaxf(cmA, __shfl_xor(cmA, 32));
    cmB = fmaxf(cmB, __shfl_xor(cmB, 32));
    const float nmA = fmaxf(mA, cmA), nmB = fmaxf(mB, cmB);
    const float fA = __expf(mA - nmA), fB = __expf(mB - nmB);
    accA[0] *= fA; accA[1] *= fA; accA[2] *= fA; accA[3] *= fA;
    accB[0] *= fB; accB[1] *= fB; accB[2] *= fB; accB[3] *= fB;
    float lsA = 0.f, lsB = 0.f;
#pragma unroll
    for (int tt = 0; tt < 4; ++tt)
#pragma unroll
      for (int r = 0; r < 4; ++r) {
        float eA = __expf(svA[tt][r] - nmA);
        float eB = __expf(svB[tt][r] - nmB);
        svA[tt][r] = eA; lsA += eA;
        svB[tt][r] = eB; lsB += eB;
      }
    lsA += __shfl_xor(lsA, 16); lsB += __shfl_xor(lsB, 16);
    lsA += __shfl_xor(lsA, 32); lsB += __shfl_xor(lsB, 32);
    lA = lA * fA + lsA; mA = nmA;
    lB = lB * fB + lsB; mB = nmB;

    // PV for both p-tiles; V fragment loaded once, used twice
#pragma unroll
    for (int tt = 0; tt < 4; ++tt) {
      U8 pA1, pA2, pB1, pB2;
#pragma unroll
      for (int r = 0; r < 4; ++r) {
        uint32_t ba = __float_as_uint(svA[tt][r]);
        uint32_t ha = ba >> 16;
        float rema = svA[tt][r] - __uint_as_float(ba & 0xFFFF0000u);
        pA1.u[r] = ha | (ha << 16);
        pA2.u[r] = __float_as_uint(rema) >> 16;
        uint32_t bb2 = __float_as_uint(svB[tt][r]);
        uint32_t hb = bb2 >> 16;
        float remb = svB[tt][r] - __uint_as_float(bb2 & 0xFFFF0000u);
        pB1.u[r] = hb | (hb << 16);
        pB2.u[r] = __float_as_uint(remb) >> 16;
      }
      short8 va = *reinterpret_cast<const short8*>(VTs + lp * 136 + tt * 32 + g * 8);
      accA = __builtin_amdgcn_mfma_f32_16x16x32_bf16(va, pA1.s8, accA, 0, 0, 0);
      accA = __builtin_amdgcn_mfma_f32_16x16x32_bf16(va, pA2.s8, accA, 0, 0, 0);
      accB = __builtin_amdgcn_mfma_f32_16x16x32_bf16(va, pB1.s8, accB, 0, 0, 0);
      accB = __builtin_amdgcn_mfma_f32_16x16x32_bf16(va, pB2.s8, accB, 0, 0, 0);
    }
  }

  const float invA = 1.f / lA, invB = 1.f / lB;
  float4 oA, oB;
  oA.x = accA[0] * invA; oA.y = accA[1] * invA; oA.z = accA[2] * invA; oA.w = accA[3] * invA;
  oB.x = accB[0] * invB; oB.y = accB[1] * invB; oB.z = accB[2] * invB; oB.w = accB[3] * invB;
  *reinterpret_cast<float4*>(O + (size_t)(b * P_ + pA) * E_ + h * 16 + g * 4) = oA;
  *reinterpret_cast<float4*>(O + (size_t)(b * P_ + pB) * E_ + h * 16 + g * 4) = oB;
}

// ---------------------------------------------------------------------------
// MFMA logits: T[b,p,n] = 10*tanh((mh[b,p,:]·enc[b,n,:])/sqrt(128)) + mask
// Same swapped layout as attention QK^T: A = enc rows (n), B = mh cols (p).
// hi/lo split-bf16, fp32->hl converted in-kernel (LDS stage for enc).
// Grid (4 n-quarters, 8 p-tiles, B). Block 256 = 4 waves x 16 p.
// ---------------------------------------------------------------------------
__global__ __launch_bounds__(256, 4) void logits_mfma(
    const float* __restrict__ mh, const float* __restrict__ enc,
    const float* __restrict__ mask, float* __restrict__ T) {
  const int b = blockIdx.z;
  const int p0 = blockIdx.y * 64;
  const int nq = blockIdx.x;           // n quarter: 256 cols
  const int tid = threadIdx.x;
  const int w = tid >> 6, lane = tid & 63;
  const int lp = lane & 15, g = lane >> 4;
  const int p = p0 + w * 16 + lp;

  __shared__ __align__(16) ushort_t Es[64 * 264];   // 64 enc rows, hl (264-el stride)

  // B fragments: this lane's mh row, 8 k-windows of 16 (lane covers g*4..g*4+3)
  U8 fb1[8], fb2[8];
  {
    const float* mrow_mh = mh + (size_t)(b * P_ + p) * E_;
#pragma unroll
    for (int win = 0; win < 8; ++win) {
      float4 v = *reinterpret_cast<const float4*>(mrow_mh + win * 16 + g * 4);
      float vv[4] = {v.x, v.y, v.z, v.w};
#pragma unroll
      for (int r = 0; r < 4; ++r) {
        uint32_t bits = __float_as_uint(vv[r]);
        uint32_t hh = bits >> 16;
        float rem = vv[r] - __uint_as_float(bits & 0xFFFF0000u);
        fb1[win].u[r] = hh | (hh << 16);
        fb2[win].u[r] = __float_as_uint(rem) >> 16;
      }
    }
  }

  const float* mrow = mask + (size_t)(b * P_ + p) * N_ + nq * 256;
  float* trow = T + (size_t)(b * P_ + p) * N_ + nq * 256;
  const float inv_s = 0.08838834764831845f;  // 1/sqrt(128)

  for (int ch = 0; ch < 4; ++ch) {           // 64 n per chunk
    const int n0g = nq * 256 + ch * 64;
    __syncthreads();
    {
      int idx = tid;
#pragma unroll
      for (int it = 0; it < 8; ++it, idx += 256) {
        const int r = idx >> 5, f4 = idx & 31;
        float4 v = *reinterpret_cast<const float4*>(
            enc + ((size_t)b * N_ + n0g + r) * E_ + f4 * 4);
        uint4 o;
        o.x = f32_to_hl(v.x); o.y = f32_to_hl(v.y);
        o.z = f32_to_hl(v.z); o.w = f32_to_hl(v.w);
        *reinterpret_cast<uint4*>(Es + r * 264 + f4 * 8) = o;
      }
    }
    __syncthreads();

#pragma unroll
    for (int tt = 0; tt < 4; ++tt) {
      f32x4 acc = {0.f, 0.f, 0.f, 0.f};
#pragma unroll
      for (int win = 0; win < 8; ++win) {
        short8 ea = *reinterpret_cast<const short8*>(
            Es + (tt * 16 + lp) * 264 + win * 32 + g * 8);
        acc = __builtin_amdgcn_mfma_f32_16x16x32_bf16(ea, fb1[win].s8, acc, 0, 0, 0);
        acc = __builtin_amdgcn_mfma_f32_16x16x32_bf16(ea, fb2[win].s8, acc, 0, 0, 0);
      }
      float4 mv = *reinterpret_cast<const float4*>(mrow + ch * 64 + tt * 16 + g * 4);
      float4 o;
      o.x = fmaf(10.f, fast_tanh(acc[0] * inv_s), mv.x);
      o.y = fmaf(10.f, fast_tanh(acc[1] * inv_s), mv.y);
      o.z = fmaf(10.f, fast_tanh(acc[2] * inv_s), mv.z);
      o.w = fmaf(10.f, fast_tanh(acc[3] * inv_s), mv.w);
      *reinterpret_cast<float4*>(trow + ch * 64 + tt * 16 + g * 4) = o;
    }
  }
}

// ---------------------------------------------------------------------------
// probs[row,:] = softmax(T[row,:] * 10)
// ---------------------------------------------------------------------------
__global__ __launch_bounds__(256, 4) void softmax_rows(
    const float* __restrict__ T, float* __restrict__ O) {
  const size_t row = blockIdx.x;
  const int tid = threadIdx.x;
  const float4 v = reinterpret_cast<const float4*>(T + row * N_)[tid];
  float lm = fmaxf(fmaxf(v.x, v.y), fmaxf(v.z, v.w));
#pragma unroll
  for (int o = 32; o; o >>= 1) lm = fmaxf(lm, __shfl_xor(lm, o));
  __shared__ float red[8];
  const int wave = tid >> 6, lane = tid & 63;
  if (lane == 0) red[wave] = lm;
  __syncthreads();
  const float m = fmaxf(fmaxf(red[0], red[1]), fmaxf(red[2], red[3]));
  float4 w;
  w.x = __expf((v.x - m) * 10.f);
  w.y = __expf((v.y - m) * 10.f);
  w.z = __expf((v.z - m) * 10.f);
  w.w = __expf((v.w - m) * 10.f);
  float ls = w.x + w.y + w.z + w.w;
#pragma unroll
  for (int o = 32; o; o >>= 1) ls += __shfl_xor(ls, o);
  if (lane == 0) red[4 + wave] = ls;
  __syncthreads();
  const float inv = 1.f / (red[4] + red[5] + red[6] + red[7]);
  float4 o4;
  o4.x = w.x * inv; o4.y = w.y * inv; o4.z = w.z * inv; o4.w = w.w * inv;
  reinterpret_cast<float4*>(O + row * N_)[tid] = o4;
}

extern "C" void kernel_launch(void* const* d_in, const int* in_sizes, int n_in,
                              void* d_out, int out_size, void* d_ws, size_t ws_size,
                              hipStream_t stream) {
  const float* eln  = (const float*)d_in[0];
  const float* load = (const float*)d_in[1];
  const float* mask = (const float*)d_in[2];
  const float* enc  = (const float*)d_in[3];
  const float* Wq   = (const float*)d_in[4];
  const float* Wk   = (const float*)d_in[5];
  const float* Wv   = (const float*)d_in[6];
  const float* Wc   = (const float*)d_in[7];
  const float* bc   = (const float*)d_in[8];
  float* out = (float*)d_out;

  // Workspace layout (bytes):
  //   khl  : 32768*256*2 = 16.78 MB   (bf16 hi/lo interleaved K)
  //   vthl :  4096*2048*2 = 16.78 MB  (bf16 hi/lo V^T per head)
  //   qhl  : 16384*256*2 =  8.39 MB   (bf16 hi/lo Q) -- reused as mhbuf (fp32)
  //   tbuf : 16384*1024*4 = 67.11 MB  (logits)  -- abuf (fp32, 8.39 MB) at head
  char* base = (char*)d_ws;
  ushort_t* khl  = (ushort_t*)base;
  ushort_t* vthl = (ushort_t*)(base + 16777216);
  ushort_t* qhl  = (ushort_t*)(base + 2 * 16777216);
  float* mhbuf   = (float*)(base + 2 * 16777216);            // overlaps qhl
  float* tbuf    = (float*)(base + 2 * 16777216 + 8388608);
  float* abuf    = tbuf;                                     // dead before logits

  // K|V projections -> bf16 hi/lo (+ V transpose)
  gemm_kv<<<dim3(256), 256, 0, stream>>>(enc, Wk, Wv, khl, vthl);
  // q = [eln | load] @ Wq_last -> bf16 hi/lo
  gemm_q<<<dim3(128), 256, 0, stream>>>(eln, Wq, load, Wq + 128 * 128, qhl);
  // MFMA flash attention (2 p-tiles per wave)
  attn_mfma<<<dim3(P_ / 128, H_, B_), 256, 0, stream>>>(qhl, khl, vthl, mask, abuf);
  // mh = attn_out @ Wc + bc   (writes over qhl region; qhl is dead)
  gemm128<<<dim3(128), 256, 0, stream>>>(abuf, Wc, nullptr, nullptr, bc, mhbuf);
  // logits = 10*tanh(mh·encT/sqrt(128)) + mask  (MFMA, overwrites abuf region)
  logits_mfma<<<dim3(4, 8, B_), 256, 0, stream>>>(mhbuf, enc, mask, tbuf);
  // probs = softmax(logits/0.1)
  softmax_rows<<<dim3(16384), 256, 0, stream>>>(tbuf, out);
}